// Round 3
// baseline (1493.319 us; speedup 1.0000x reference)
//
#include <hip/hip_runtime.h>
#include <hip/hip_bf16.h>

typedef __hip_bfloat16 bf16;

static constexpr int N_ = 50000;   // nodes
static constexpr int E_ = 20000;   // hyperedges
static constexpr int M_ = 320000;  // incidence pairs

__device__ __forceinline__ float b2f(bf16 v){ return __bfloat162float(v); }
__device__ __forceinline__ float sigm(float x){ return 1.f/(1.f+__expf(-x)); }

// ---------------- dtype sniff: are float tensors stored as bf16 or fp32? ----------------
__global__ __launch_bounds__(256) void k_sniff(const unsigned short* __restrict__ xb, int* flag){
  int tid = threadIdx.x;
  int sane = 0;
  for (int i = tid; i < 4096; i += 256){
    unsigned short u = xb[2*i];
    int ex = (u >> 7) & 0xFF;
    if ((u & 0x7FFF) == 0 || (ex >= 117 && ex <= 137)) sane++;   // |v| in ~[2^-10, 2^10] or 0
  }
  #pragma unroll
  for (int d=1; d<64; d<<=1) sane += __shfl_xor(sane, d, 64);
  __shared__ int wsh[4];
  if ((tid&63)==0) wsh[tid>>6] = sane;
  __syncthreads();
  if (tid==0){
    int tot = wsh[0]+wsh[1]+wsh[2]+wsh[3];
    *flag = (tot > 2048) ? 1 : 0;    // 1 = bf16 storage
  }
}

// ---------------- generic convert to fp32 ----------------
__global__ __launch_bounds__(256) void k_cvt(const void* __restrict__ src, float* __restrict__ dst,
                                             int n, const int* __restrict__ flag){
  int i = blockIdx.x*256 + threadIdx.x;
  if (i >= n) return;
  if (*flag) dst[i] = b2f(((const bf16*)src)[i]);
  else       dst[i] = ((const float*)src)[i];
}

__global__ __launch_bounds__(256) void k_zero(int* p, int n){
  int i = blockIdx.x*256 + threadIdx.x; if (i<n) p[i]=0;
}

// ---------------- CSR build ----------------
__global__ __launch_bounds__(256) void k_hist(const int* __restrict__ eidx, const int* __restrict__ nidx,
                                              int* cnt_e, int* cnt_n){
  int m = blockIdx.x*256 + threadIdx.x;
  if (m < M_){ atomicAdd(&cnt_e[eidx[m]],1); atomicAdd(&cnt_n[nidx[m]],1); }
}

__global__ __launch_bounds__(1024) void k_scan(const int* __restrict__ cnt, int* __restrict__ off,
                                               int* __restrict__ cur, int n){
  __shared__ int wsum[16];
  __shared__ int wpre[16];
  int tid = threadIdx.x, lane = tid&63, wid = tid>>6;
  int carry = 0;
  for (int base=0; base<n; base+=1024){
    int i = base + tid;
    int v = (i<n)? cnt[i] : 0;
    int s = v;
    #pragma unroll
    for (int d=1; d<64; d<<=1){ int t = __shfl_up(s, d, 64); if (lane>=d) s += t; }
    if (lane==63) wsum[wid] = s;
    __syncthreads();
    if (wid==0 && lane<16){
      int a = wsum[lane]; int ps = a;
      #pragma unroll
      for (int d=1; d<16; d<<=1){ int t = __shfl_up(ps, d, 64); if (lane>=d) ps += t; }
      wpre[lane] = ps - a;
    }
    __syncthreads();
    int excl = carry + wpre[wid] + (s - v);
    if (i<n){ off[i]=excl; cur[i]=excl; }
    carry += wpre[15] + wsum[15];
    __syncthreads();
  }
  if (tid==0) off[n] = carry;
}

__global__ __launch_bounds__(256) void k_fill(const int* __restrict__ eidx, const int* __restrict__ nidx,
                                              int* cur_e, int* cur_n, int* ep, int* np){
  int m = blockIdx.x*256 + threadIdx.x;
  if (m < M_){
    int p = atomicAdd(&cur_e[eidx[m]],1); ep[p]=m;
    int q = atomicAdd(&cur_n[nidx[m]],1); np[q]=m;
  }
}

// ---------------- pre[l][t][h*32+k] = b1 + sum_d tq[l,h,t,d]*w1[l,h,k,256+d] ----------------
__global__ __launch_bounds__(256) void k_pre(const float* __restrict__ tq, const float* __restrict__ w1,
                                             const float* __restrict__ b1, float* __restrict__ pre){
  int idx = blockIdx.x*256 + threadIdx.x;
  if (idx >= 768) return;
  int l = idx / 384, r = idx % 384;
  int t = r / 128, r2 = r % 128;          // r2 = h*32+k
  int h = r2 >> 5, k = r2 & 31;
  const float* tp = tq + ((l*4+h)*3 + t)*64;
  const float* wp = w1 + (size_t)((l*4+h)*32 + k)*320 + 256;
  float s = b1[(l*4+h)*32 + k];
  for (int d=0; d<64; ++d) s += tp[d]*wp[d];
  pre[(l*3+t)*128 + r2] = s;
}

// ---------------- wqe[l][h*3+t][d] = sum_o ec[l,h,t,o] * wq[l,h,o,d] ----------------
__global__ __launch_bounds__(256) void k_wqe(const float* __restrict__ wq_f, const float* __restrict__ ec_f,
                                             float* __restrict__ wqe){
  int b = blockIdx.x;          // 0..23 = l*12 + h*3 + t
  int l = b/12, ht = b%12, h = ht/3, t = ht%3;
  int d = threadIdx.x;
  const float* ecp = ec_f + ((l*4+h)*3 + t)*64;
  const float* wqp = wq_f + (size_t)((l*4+h)*64)*256;    // [o][d]
  float s = 0.f;
  for (int o=0;o<64;++o) s += ecp[o]*wqp[o*256 + d];
  wqe[(size_t)(l*12+ht)*256 + d] = s;
}

// ---------------- fused GEMM: [N,256] x [256,396] -> V(256) | Hgate(128) | S(12) ----------------
__global__ __launch_bounds__(256) void k_gemm(const float* __restrict__ hbuf,
    const float* __restrict__ wvp, const float* __restrict__ w1p, const float* __restrict__ wqep,
    float* __restrict__ Vb, float* __restrict__ Hb, float* __restrict__ S){
  __shared__ float As[32][65];
  __shared__ float Bs[32][65];
  int tid = threadIdx.x;
  int row0 = blockIdx.x*64, col0 = blockIdx.y*64;
  int tx = tid & 15, ty = tid >> 4;
  int rr = ty*4, cc = tx*4;
  float acc[4][4] = {{0.f}};
  for (int kc=0; kc<256; kc+=32){
    #pragma unroll
    for (int p=0;p<8;p++){
      int idx = tid + p*256;
      int kl = idx & 31, r = idx >> 5;
      int grow = row0 + r;
      As[kl][r] = (grow < N_) ? hbuf[(size_t)grow*256 + kc + kl] : 0.f;
    }
    #pragma unroll
    for (int p=0;p<8;p++){
      int idx = tid + p*256;
      int kl = idx & 31, c = idx >> 5;
      int cg = col0 + c;
      float bv = 0.f;
      if (cg < 256)      bv = wvp[(size_t)cg*256 + kc + kl];
      else if (cg < 384) bv = w1p[(size_t)(cg-256)*320 + kc + kl];
      else if (cg < 396) bv = wqep[(size_t)(cg-384)*256 + kc + kl];
      Bs[kl][c] = bv;
    }
    __syncthreads();
    #pragma unroll
    for (int k=0;k<32;k++){
      float a0=As[k][rr+0], a1=As[k][rr+1], a2=As[k][rr+2], a3=As[k][rr+3];
      float c0=Bs[k][cc+0], c1=Bs[k][cc+1], c2=Bs[k][cc+2], c3=Bs[k][cc+3];
      acc[0][0]+=a0*c0; acc[0][1]+=a0*c1; acc[0][2]+=a0*c2; acc[0][3]+=a0*c3;
      acc[1][0]+=a1*c0; acc[1][1]+=a1*c1; acc[1][2]+=a1*c2; acc[1][3]+=a1*c3;
      acc[2][0]+=a2*c0; acc[2][1]+=a2*c1; acc[2][2]+=a2*c2; acc[2][3]+=a2*c3;
      acc[3][0]+=a3*c0; acc[3][1]+=a3*c1; acc[3][2]+=a3*c2; acc[3][3]+=a3*c3;
    }
    __syncthreads();
  }
  #pragma unroll
  for (int i=0;i<4;i++){
    int grow = row0+rr+i; if (grow>=N_) continue;
    #pragma unroll
    for (int j=0;j<4;j++){
      int cg = col0+cc+j; float v = acc[i][j];
      if (cg < 256)      Vb[(size_t)grow*256 + cg]       = v;
      else if (cg < 384) Hb[(size_t)grow*128 + cg - 256] = v;
      else if (cg < 396) S [(size_t)grow*12  + cg - 384] = v;
    }
  }
}

// ---------------- per-node gate: G[n,t,h] = lrelu(S[n,h,t]) * sigmoid(gate[n,h]) ----------------
__global__ __launch_bounds__(256) void k_gate(const float* __restrict__ Hb, const float* __restrict__ S,
    const float* __restrict__ pre_l, const float* __restrict__ w2_l, const float* __restrict__ b2_l,
    const int* __restrict__ ntype, float* __restrict__ G){
  int node = blockIdx.x*4 + (threadIdx.x>>6);
  int lane = threadIdx.x & 63;
  if (node >= N_) return;
  int typ = ntype[node];
  const float* pr = pre_l + typ*128;
  float v0 = tanhf(Hb[(size_t)node*128 + lane]      + pr[lane]);
  float v1 = tanhf(Hb[(size_t)node*128 + 64 + lane] + pr[64+lane]);
  float p0 = v0 * w2_l[lane];
  float p1 = v1 * w2_l[64+lane];
  #pragma unroll
  for (int d=1; d<32; d<<=1){ p0 += __shfl_xor(p0,d,64); p1 += __shfl_xor(p1,d,64); }
  float at0 = sigm(__shfl(p0, 0,64) + b2_l[0]);
  float at1 = sigm(__shfl(p0,32,64) + b2_l[1]);
  float at2 = sigm(__shfl(p1, 0,64) + b2_l[2]);
  float at3 = sigm(__shfl(p1,32,64) + b2_l[3]);
  if (lane < 12){
    int h = lane / 3, t = lane % 3;       // S col order = h*3+t
    float sv = S[(size_t)node*12 + lane];
    float lr = (sv > 0.f) ? sv : 0.2f*sv;
    float av = (h==0)? at0 : (h==1)? at1 : (h==2)? at2 : at3;
    G[(size_t)node*12 + t*4 + h] = lr * av;   // G layout: [n][t][4 heads] for float4 loads
  }
}

// ---------------- per-edge softmax + edge_feat (wave per edge, no atomics) ----------------
__global__ __launch_bounds__(256) void k_edge(const int* __restrict__ eoff, const int* __restrict__ ep,
    const int* __restrict__ nidx, const int* __restrict__ etype,
    const float* __restrict__ G, const float* __restrict__ Vb,
    float* __restrict__ attn, float* __restrict__ EF){
  int e = blockIdx.x*4 + (threadIdx.x>>6);
  int lane = threadIdx.x & 63;
  if (e >= E_) return;
  int beg = eoff[e], end = eoff[e+1];
  if (beg == end) return;
  int t = etype[e];
  float mx0=-1e30f, mx1=-1e30f, mx2=-1e30f, mx3=-1e30f;
  for (int i=beg+lane; i<end; i+=64){
    int m = ep[i]; int n = nidx[m];
    float4 g = *(const float4*)(G + (size_t)n*12 + t*4);
    mx0=fmaxf(mx0,g.x); mx1=fmaxf(mx1,g.y); mx2=fmaxf(mx2,g.z); mx3=fmaxf(mx3,g.w);
  }
  #pragma unroll
  for (int d=1; d<64; d<<=1){
    mx0=fmaxf(mx0,__shfl_xor(mx0,d,64)); mx1=fmaxf(mx1,__shfl_xor(mx1,d,64));
    mx2=fmaxf(mx2,__shfl_xor(mx2,d,64)); mx3=fmaxf(mx3,__shfl_xor(mx3,d,64));
  }
  float sm0=0,sm1=0,sm2=0,sm3=0;
  for (int i=beg+lane; i<end; i+=64){
    int m = ep[i]; int n = nidx[m];
    float4 g = *(const float4*)(G + (size_t)n*12 + t*4);
    sm0+=__expf(g.x-mx0); sm1+=__expf(g.y-mx1); sm2+=__expf(g.z-mx2); sm3+=__expf(g.w-mx3);
  }
  #pragma unroll
  for (int d=1; d<64; d<<=1){
    sm0+=__shfl_xor(sm0,d,64); sm1+=__shfl_xor(sm1,d,64);
    sm2+=__shfl_xor(sm2,d,64); sm3+=__shfl_xor(sm3,d,64);
  }
  float inv0=1.f/sm0, inv1=1.f/sm1, inv2=1.f/sm2, inv3=1.f/sm3;
  for (int i=beg+lane; i<end; i+=64){
    int m = ep[i]; int n = nidx[m];
    float4 g = *(const float4*)(G + (size_t)n*12 + t*4);
    float4 w;
    w.x=__expf(g.x-mx0)*inv0; w.y=__expf(g.y-mx1)*inv1;
    w.z=__expf(g.z-mx2)*inv2; w.w=__expf(g.w-mx3)*inv3;
    *(float4*)(attn + (size_t)m*4) = w;
  }
  float e0=0,e1=0,e2=0,e3=0;
  for (int i=beg; i<end; ++i){
    int m = ep[i]; int n = nidx[m];
    float4 g = *(const float4*)(G + (size_t)n*12 + t*4);
    float w0=__expf(g.x-mx0)*inv0, w1=__expf(g.y-mx1)*inv1;
    float w2=__expf(g.z-mx2)*inv2, w3=__expf(g.w-mx3)*inv3;
    const float* vp = Vb + (size_t)n*256;
    e0 += w0*vp[lane]; e1 += w1*vp[64+lane]; e2 += w2*vp[128+lane]; e3 += w3*vp[192+lane];
  }
  float* efp = EF + (size_t)e*256;
  efp[lane]=e0; efp[64+lane]=e1; efp[128+lane]=e2; efp[192+lane]=e3;
}

// ---------------- per-node gather + residual + LayerNorm (wave per node) ----------------
__global__ __launch_bounds__(256) void k_node(const int* __restrict__ noff, const int* __restrict__ np,
    const int* __restrict__ eidx, const float* __restrict__ attn, const float* __restrict__ EF,
    const float* __restrict__ lng, const float* __restrict__ lnb,
    float* __restrict__ hio, void* __restrict__ outv, const int* __restrict__ flag, int last){
  int n = blockIdx.x*4 + (threadIdx.x>>6);
  int lane = threadIdx.x & 63;
  if (n >= N_) return;
  float f0=0,f1=0,f2=0,f3=0;
  int beg = noff[n], end = noff[n+1];
  for (int i=beg; i<end; ++i){
    int m = np[i]; int e = eidx[m];
    float4 w = *(const float4*)(attn + (size_t)m*4);
    const float* ef = EF + (size_t)e*256;
    f0 += w.x*ef[lane]; f1 += w.y*ef[64+lane]; f2 += w.z*ef[128+lane]; f3 += w.w*ef[192+lane];
  }
  const float* hp = hio + (size_t)n*256;
  float h0 = hp[lane]+f0, h1 = hp[64+lane]+f1, h2 = hp[128+lane]+f2, h3 = hp[192+lane]+f3;
  float s = h0+h1+h2+h3;
  #pragma unroll
  for (int d=1; d<64; d<<=1) s += __shfl_xor(s,d,64);
  float mean = s * (1.f/256.f);
  float d0=h0-mean, d1=h1-mean, d2=h2-mean, d3=h3-mean;
  float vv = d0*d0+d1*d1+d2*d2+d3*d3;
  #pragma unroll
  for (int d=1; d<64; d<<=1) vv += __shfl_xor(vv,d,64);
  float rstd = rsqrtf(vv*(1.f/256.f) + 1e-5f);
  float o0 = d0*rstd*lng[lane]     + lnb[lane];
  float o1 = d1*rstd*lng[64+lane]  + lnb[64+lane];
  float o2 = d2*rstd*lng[128+lane] + lnb[128+lane];
  float o3 = d3*rstd*lng[192+lane] + lnb[192+lane];
  if (last){
    if (*flag){
      bf16* op = (bf16*)outv + (size_t)n*256;
      op[lane]=__float2bfloat16(o0); op[64+lane]=__float2bfloat16(o1);
      op[128+lane]=__float2bfloat16(o2); op[192+lane]=__float2bfloat16(o3);
    } else {
      float* op = (float*)outv + (size_t)n*256;
      op[lane]=o0; op[64+lane]=o1; op[128+lane]=o2; op[192+lane]=o3;
    }
  } else {
    float* op = hio + (size_t)n*256;
    op[lane]=o0; op[64+lane]=o1; op[128+lane]=o2; op[192+lane]=o3;
  }
}

extern "C" void kernel_launch(void* const* d_in, const int* in_sizes, int n_in,
                              void* d_out, int out_size, void* d_ws, size_t ws_size,
                              hipStream_t stream){
  const void* x    = d_in[0];
  const int* ntype = (const int*)d_in[1];
  const int* etype = (const int*)d_in[2];
  const int* nidx  = (const int*)d_in[3];
  const int* eidx  = (const int*)d_in[4];
  (void)in_sizes; (void)n_in; (void)out_size; (void)ws_size;

  char* ws = (char*)d_ws;
  size_t o = 0;
  auto alloc = [&](size_t b)->char*{ char* r = ws + o; o = (o + b + 255) & ~(size_t)255; return r; };
  int*   flag = (int*)  alloc(256);
  float* hbuf = (float*)alloc((size_t)N_*256*4);          // 51.2 MB fp32 hidden state
  float* Vb   = (float*)alloc((size_t)N_*256*4);          // 51.2 MB
  char*  R2   =         alloc((size_t)28000000);          // Hb(25.6M)+S(2.4M), reused as attn+EF
  float* G    = (float*)alloc((size_t)N_*12*4);
  // fp32 weight staging
  float* tq_f  = (float*)alloc(1536*4);
  float* w1_f  = (float*)alloc(81920*4);
  float* b1_f  = (float*)alloc(256*4);
  float* w2_f  = (float*)alloc(256*4);
  float* b2_f  = (float*)alloc(8*4);
  float* wq_f  = (float*)alloc(131072*4);
  float* wv_f  = (float*)alloc(131072*4);
  float* ec_f  = (float*)alloc(1536*4);
  float* lng_f = (float*)alloc(512*4);
  float* lnb_f = (float*)alloc(512*4);
  float* wqe   = (float*)alloc(6144*4);
  float* pre   = (float*)alloc(768*4);
  int* cnt_e  = (int*)alloc((size_t)E_*4);
  int* cnt_n  = (int*)alloc((size_t)N_*4);
  int* eoff   = (int*)alloc((size_t)(E_+1)*4);
  int* noff   = (int*)alloc((size_t)(N_+1)*4);
  int* cur_e  = (int*)alloc((size_t)E_*4);
  int* cur_n  = (int*)alloc((size_t)N_*4);
  int* ep     = (int*)alloc((size_t)M_*4);
  int* np     = (int*)alloc((size_t)M_*4);

  float* Hb   = (float*)R2;                                // 25.6 MB
  float* S    = (float*)(R2 + 25600000);                   // 2.4 MB
  float* attn = (float*)R2;                                // 5.12 MB (after gate consumed Hb)
  float* EF   = (float*)(R2 + (size_t)M_*4*4);             // 20.48 MB, ends exactly at S

  k_sniff<<<1, 256, 0, stream>>>((const unsigned short*)x, flag);
  k_cvt<<<(N_*256+255)/256, 256, 0, stream>>>(x, hbuf, N_*256, flag);
  k_cvt<<<(1536+255)/256,   256, 0, stream>>>(d_in[5],  tq_f,  1536,   flag);
  k_cvt<<<(81920+255)/256,  256, 0, stream>>>(d_in[6],  w1_f,  81920,  flag);
  k_cvt<<<1,                256, 0, stream>>>(d_in[7],  b1_f,  256,    flag);
  k_cvt<<<1,                256, 0, stream>>>(d_in[8],  w2_f,  256,    flag);
  k_cvt<<<1,                256, 0, stream>>>(d_in[9],  b2_f,  8,      flag);
  k_cvt<<<(131072+255)/256, 256, 0, stream>>>(d_in[10], wq_f,  131072, flag);
  k_cvt<<<(131072+255)/256, 256, 0, stream>>>(d_in[11], wv_f,  131072, flag);
  k_cvt<<<(1536+255)/256,   256, 0, stream>>>(d_in[12], ec_f,  1536,   flag);
  k_cvt<<<2,                256, 0, stream>>>(d_in[13], lng_f, 512,    flag);   // FIX: was 1 block for 512 elems
  k_cvt<<<2,                256, 0, stream>>>(d_in[14], lnb_f, 512,    flag);   // FIX: was 1 block for 512 elems

  k_zero<<<(E_+255)/256, 256, 0, stream>>>(cnt_e, E_);
  k_zero<<<(N_+255)/256, 256, 0, stream>>>(cnt_n, N_);
  k_hist<<<M_/256, 256, 0, stream>>>(eidx, nidx, cnt_e, cnt_n);
  k_scan<<<1, 1024, 0, stream>>>(cnt_e, eoff, cur_e, E_);
  k_scan<<<1, 1024, 0, stream>>>(cnt_n, noff, cur_n, N_);
  k_fill<<<M_/256, 256, 0, stream>>>(eidx, nidx, cur_e, cur_n, ep, np);
  k_pre<<<3, 256, 0, stream>>>(tq_f, w1_f, b1_f, pre);
  k_wqe<<<24, 256, 0, stream>>>(wq_f, ec_f, wqe);

  for (int l=0; l<2; ++l){
    k_gemm<<<dim3(782,7), 256, 0, stream>>>(hbuf, wv_f + (size_t)l*65536,
                                            w1_f + (size_t)l*40960, wqe + (size_t)l*3072,
                                            Vb, Hb, S);
    k_gate<<<12500, 256, 0, stream>>>(Hb, S, pre + l*384, w2_f + l*128, b2_f + l*4, ntype, G);
    k_edge<<<5000, 256, 0, stream>>>(eoff, ep, nidx, etype, G, Vb, attn, EF);
    k_node<<<12500, 256, 0, stream>>>(noff, np, eidx, attn, EF, lng_f + l*256, lnb_f + l*256,
                                      hbuf, d_out, flag, l==1);
  }
}

// Round 4
// 805.665 us; speedup vs baseline: 1.8535x; 1.8535x over previous
//
#include <hip/hip_runtime.h>
#include <hip/hip_bf16.h>

typedef __hip_bfloat16 bf16;
using short8  = __attribute__((ext_vector_type(8))) short;
using float4v = __attribute__((ext_vector_type(4))) float;

static constexpr int N_ = 50000;   // nodes
static constexpr int E_ = 20000;   // hyperedges
static constexpr int M_ = 320000;  // incidence pairs
static constexpr int NPAD_ = 50048;  // 391*128 rows for MFMA grid

__device__ __forceinline__ float b2f(bf16 v){ return __bfloat162float(v); }
__device__ __forceinline__ float sigm(float x){ return 1.f/(1.f+__expf(-x)); }

// ---------------- dtype sniff: are float tensors stored as bf16 or fp32? ----------------
__global__ __launch_bounds__(256) void k_sniff(const unsigned short* __restrict__ xb, int* flag){
  int tid = threadIdx.x;
  int sane = 0;
  for (int i = tid; i < 4096; i += 256){
    unsigned short u = xb[2*i];
    int ex = (u >> 7) & 0xFF;
    if ((u & 0x7FFF) == 0 || (ex >= 117 && ex <= 137)) sane++;
  }
  #pragma unroll
  for (int d=1; d<64; d<<=1) sane += __shfl_xor(sane, d, 64);
  __shared__ int wsh[4];
  if ((tid&63)==0) wsh[tid>>6] = sane;
  __syncthreads();
  if (tid==0){
    int tot = wsh[0]+wsh[1]+wsh[2]+wsh[3];
    *flag = (tot > 2048) ? 1 : 0;    // 1 = bf16 storage
  }
}

// ---------------- generic converts ----------------
__global__ __launch_bounds__(256) void k_cvt(const void* __restrict__ src, float* __restrict__ dst,
                                             int n, const int* __restrict__ flag){
  int i = blockIdx.x*256 + threadIdx.x;
  if (i >= n) return;
  if (*flag) dst[i] = b2f(((const bf16*)src)[i]);
  else       dst[i] = ((const float*)src)[i];
}

__global__ __launch_bounds__(256) void k_cvt16(const void* __restrict__ src, bf16* __restrict__ dst,
                                               int n, const int* __restrict__ flag){
  int i = blockIdx.x*256 + threadIdx.x;
  if (i >= n) return;
  if (*flag) dst[i] = ((const bf16*)src)[i];
  else       dst[i] = __float2bfloat16(((const float*)src)[i]);
}

__global__ __launch_bounds__(256) void k_zero(int* p, int n){
  int i = blockIdx.x*256 + threadIdx.x; if (i<n) p[i]=0;
}

// ---------------- CSR build ----------------
__global__ __launch_bounds__(256) void k_hist(const int* __restrict__ eidx, const int* __restrict__ nidx,
                                              int* cnt_e, int* cnt_n){
  int m = blockIdx.x*256 + threadIdx.x;
  if (m < M_){ atomicAdd(&cnt_e[eidx[m]],1); atomicAdd(&cnt_n[nidx[m]],1); }
}

__global__ __launch_bounds__(1024) void k_scan(const int* __restrict__ cnt, int* __restrict__ off,
                                               int* __restrict__ cur, int n){
  __shared__ int wsum[16];
  __shared__ int wpre[16];
  int tid = threadIdx.x, lane = tid&63, wid = tid>>6;
  int carry = 0;
  for (int base=0; base<n; base+=1024){
    int i = base + tid;
    int v = (i<n)? cnt[i] : 0;
    int s = v;
    #pragma unroll
    for (int d=1; d<64; d<<=1){ int t = __shfl_up(s, d, 64); if (lane>=d) s += t; }
    if (lane==63) wsum[wid] = s;
    __syncthreads();
    if (wid==0 && lane<16){
      int a = wsum[lane]; int ps = a;
      #pragma unroll
      for (int d=1; d<16; d<<=1){ int t = __shfl_up(ps, d, 64); if (lane>=d) ps += t; }
      wpre[lane] = ps - a;
    }
    __syncthreads();
    int excl = carry + wpre[wid] + (s - v);
    if (i<n){ off[i]=excl; cur[i]=excl; }
    carry += wpre[15] + wsum[15];
    __syncthreads();
  }
  if (tid==0) off[n] = carry;
}

__global__ __launch_bounds__(256) void k_fill(const int* __restrict__ eidx, const int* __restrict__ nidx,
                                              int* cur_e, int* cur_n, int* ep, int* np){
  int m = blockIdx.x*256 + threadIdx.x;
  if (m < M_){
    int p = atomicAdd(&cur_e[eidx[m]],1); ep[p]=m;
    int q = atomicAdd(&cur_n[nidx[m]],1); np[q]=m;
  }
}

// ---------------- pre[l][t][h*32+k] = b1 + sum_d tq[l,h,t,d]*w1[l,h,k,256+d] ----------------
__global__ __launch_bounds__(256) void k_pre(const float* __restrict__ tq, const float* __restrict__ w1,
                                             const float* __restrict__ b1, float* __restrict__ pre){
  int idx = blockIdx.x*256 + threadIdx.x;
  if (idx >= 768) return;
  int l = idx / 384, r = idx % 384;
  int t = r / 128, r2 = r % 128;          // r2 = h*32+k
  int h = r2 >> 5, k = r2 & 31;
  const float* tp = tq + ((l*4+h)*3 + t)*64;
  const float* wp = w1 + (size_t)((l*4+h)*32 + k)*320 + 256;
  float s = b1[(l*4+h)*32 + k];
  for (int d=0; d<64; ++d) s += tp[d]*wp[d];
  pre[(l*3+t)*128 + r2] = s;
}

// ---------------- wqe[l][h*3+t][d] = sum_o ec[l,h,t,o] * wq[l,h,o,d] ----------------
__global__ __launch_bounds__(256) void k_wqe(const float* __restrict__ wq_f, const float* __restrict__ ec_f,
                                             float* __restrict__ wqe){
  int b = blockIdx.x;          // 0..23 = l*12 + h*3 + t
  int l = b/12, ht = b%12, h = ht/3, t = ht%3;
  int d = threadIdx.x;
  const float* ecp = ec_f + ((l*4+h)*3 + t)*64;
  const float* wqp = wq_f + (size_t)((l*4+h)*64)*256;    // [o][d]
  float s = 0.f;
  for (int o=0;o<64;++o) s += ecp[o]*wqp[o*256 + d];
  wqe[(size_t)(l*12+ht)*256 + d] = s;
}

// ---------------- pack B panel: Bp[l][448][256] bf16 = wv | w1[:,:256] | wqe | 0 ----------------
__global__ __launch_bounds__(256) void k_bpack(const float* __restrict__ wv_f, const float* __restrict__ w1_f,
                                               const float* __restrict__ wqe, bf16* __restrict__ Bp){
  int idx = blockIdx.x*256 + threadIdx.x;
  if (idx >= 2*448*256) return;
  int l = idx / (448*256), r = idx % (448*256);
  int c = r >> 8, k = r & 255;
  float v = 0.f;
  if (c < 256)      v = wv_f[(size_t)l*65536 + (size_t)c*256 + k];
  else if (c < 384) v = w1_f[(size_t)l*40960 + (size_t)(c-256)*320 + k];
  else if (c < 396) v = wqe[(size_t)(l*12 + c-384)*256 + k];
  Bp[idx] = __float2bfloat16(v);
}

// ---------------- MFMA GEMM: [NPAD,256]bf16 x [256,448]bf16 -> V(256)|Hgate(128)|S(12) fp32 ----------------
// grid (7, 391), block 256 = 4 waves; wave owns 32 rows (2 m-tiles), block owns 64 cols (4 n-tiles).
// Zero LDS: a-frags read once per block; B panel (229 KB) is L2-resident.
__global__ __launch_bounds__(256) void k_mgemm(const bf16* __restrict__ A16, const bf16* __restrict__ Bp,
    float* __restrict__ Vb, float* __restrict__ Hb, float* __restrict__ S){
  int wid = threadIdx.x >> 6, lane = threadIdx.x & 63;
  int q = lane >> 4, li = lane & 15;
  int row0 = blockIdx.y*128 + wid*32;
  int col0 = blockIdx.x*64;
  float4v acc[2][4];
  #pragma unroll
  for (int i=0;i<2;i++)
    #pragma unroll
    for (int j=0;j<4;j++) acc[i][j] = (float4v)(0.f);
  const bf16* a0p = A16 + (size_t)(row0 + li)*256;
  const bf16* a1p = A16 + (size_t)(row0 + 16 + li)*256;
  const bf16* bp  = Bp  + (size_t)(col0 + li)*256;
  #pragma unroll
  for (int kc=0; kc<256; kc+=32){
    int ko = kc + q*8;
    short8 a0 = *(const short8*)(a0p + ko);
    short8 a1 = *(const short8*)(a1p + ko);
    short8 b0 = *(const short8*)(bp + ko);
    short8 b1 = *(const short8*)(bp + 16*256 + ko);
    short8 b2 = *(const short8*)(bp + 32*256 + ko);
    short8 b3 = *(const short8*)(bp + 48*256 + ko);
    acc[0][0] = __builtin_amdgcn_mfma_f32_16x16x32_bf16(a0,b0,acc[0][0],0,0,0);
    acc[0][1] = __builtin_amdgcn_mfma_f32_16x16x32_bf16(a0,b1,acc[0][1],0,0,0);
    acc[0][2] = __builtin_amdgcn_mfma_f32_16x16x32_bf16(a0,b2,acc[0][2],0,0,0);
    acc[0][3] = __builtin_amdgcn_mfma_f32_16x16x32_bf16(a0,b3,acc[0][3],0,0,0);
    acc[1][0] = __builtin_amdgcn_mfma_f32_16x16x32_bf16(a1,b0,acc[1][0],0,0,0);
    acc[1][1] = __builtin_amdgcn_mfma_f32_16x16x32_bf16(a1,b1,acc[1][1],0,0,0);
    acc[1][2] = __builtin_amdgcn_mfma_f32_16x16x32_bf16(a1,b2,acc[1][2],0,0,0);
    acc[1][3] = __builtin_amdgcn_mfma_f32_16x16x32_bf16(a1,b3,acc[1][3],0,0,0);
  }
  // D layout: row = quad*4 + reg, col = lane&15  [m89/m91 verified]
  #pragma unroll
  for (int i=0;i<2;i++){
    #pragma unroll
    for (int r=0;r<4;r++){
      int grow = row0 + i*16 + q*4 + r;
      if (grow >= N_) continue;
      #pragma unroll
      for (int j=0;j<4;j++){
        int gc = col0 + j*16 + li;
        float v = acc[i][j][r];
        if (gc < 256)      Vb[(size_t)grow*256 + gc]       = v;
        else if (gc < 384) Hb[(size_t)grow*128 + gc - 256] = v;
        else if (gc < 396) S [(size_t)grow*12  + gc - 384] = v;
      }
    }
  }
}

// ---------------- per-node gate: G[n,t,h] = lrelu(S[n,h,t]) * sigmoid(gate[n,h]) ----------------
__global__ __launch_bounds__(256) void k_gate(const float* __restrict__ Hb, const float* __restrict__ S,
    const float* __restrict__ pre_l, const float* __restrict__ w2_l, const float* __restrict__ b2_l,
    const int* __restrict__ ntype, float* __restrict__ G){
  int node = blockIdx.x*4 + (threadIdx.x>>6);
  int lane = threadIdx.x & 63;
  if (node >= N_) return;
  int typ = ntype[node];
  const float* pr = pre_l + typ*128;
  float v0 = tanhf(Hb[(size_t)node*128 + lane]      + pr[lane]);
  float v1 = tanhf(Hb[(size_t)node*128 + 64 + lane] + pr[64+lane]);
  float p0 = v0 * w2_l[lane];
  float p1 = v1 * w2_l[64+lane];
  #pragma unroll
  for (int d=1; d<32; d<<=1){ p0 += __shfl_xor(p0,d,64); p1 += __shfl_xor(p1,d,64); }
  float at0 = sigm(__shfl(p0, 0,64) + b2_l[0]);
  float at1 = sigm(__shfl(p0,32,64) + b2_l[1]);
  float at2 = sigm(__shfl(p1, 0,64) + b2_l[2]);
  float at3 = sigm(__shfl(p1,32,64) + b2_l[3]);
  if (lane < 12){
    int h = lane / 3, t = lane % 3;       // S col order = h*3+t
    float sv = S[(size_t)node*12 + lane];
    float lr = (sv > 0.f) ? sv : 0.2f*sv;
    float av = (h==0)? at0 : (h==1)? at1 : (h==2)? at2 : at3;
    G[(size_t)node*12 + t*4 + h] = lr * av;   // G layout: [n][t][4 heads]
  }
}

// ---------------- per-edge softmax + edge_feat (wave per edge, no atomics) ----------------
__global__ __launch_bounds__(256) void k_edge(const int* __restrict__ eoff, const int* __restrict__ ep,
    const int* __restrict__ nidx, const int* __restrict__ etype,
    const float* __restrict__ G, const float* __restrict__ Vb,
    float* __restrict__ attn, float* __restrict__ EF){
  int e = blockIdx.x*4 + (threadIdx.x>>6);
  int lane = threadIdx.x & 63;
  if (e >= E_) return;
  int beg = eoff[e], end = eoff[e+1];
  if (beg == end) return;
  int t = etype[e];
  float mx0=-1e30f, mx1=-1e30f, mx2=-1e30f, mx3=-1e30f;
  for (int i=beg+lane; i<end; i+=64){
    int m = ep[i]; int n = nidx[m];
    float4 g = *(const float4*)(G + (size_t)n*12 + t*4);
    mx0=fmaxf(mx0,g.x); mx1=fmaxf(mx1,g.y); mx2=fmaxf(mx2,g.z); mx3=fmaxf(mx3,g.w);
  }
  #pragma unroll
  for (int d=1; d<64; d<<=1){
    mx0=fmaxf(mx0,__shfl_xor(mx0,d,64)); mx1=fmaxf(mx1,__shfl_xor(mx1,d,64));
    mx2=fmaxf(mx2,__shfl_xor(mx2,d,64)); mx3=fmaxf(mx3,__shfl_xor(mx3,d,64));
  }
  float sm0=0,sm1=0,sm2=0,sm3=0;
  for (int i=beg+lane; i<end; i+=64){
    int m = ep[i]; int n = nidx[m];
    float4 g = *(const float4*)(G + (size_t)n*12 + t*4);
    sm0+=__expf(g.x-mx0); sm1+=__expf(g.y-mx1); sm2+=__expf(g.z-mx2); sm3+=__expf(g.w-mx3);
  }
  #pragma unroll
  for (int d=1; d<64; d<<=1){
    sm0+=__shfl_xor(sm0,d,64); sm1+=__shfl_xor(sm1,d,64);
    sm2+=__shfl_xor(sm2,d,64); sm3+=__shfl_xor(sm3,d,64);
  }
  float inv0=1.f/sm0, inv1=1.f/sm1, inv2=1.f/sm2, inv3=1.f/sm3;
  for (int i=beg+lane; i<end; i+=64){
    int m = ep[i]; int n = nidx[m];
    float4 g = *(const float4*)(G + (size_t)n*12 + t*4);
    float4 w;
    w.x=__expf(g.x-mx0)*inv0; w.y=__expf(g.y-mx1)*inv1;
    w.z=__expf(g.z-mx2)*inv2; w.w=__expf(g.w-mx3)*inv3;
    *(float4*)(attn + (size_t)m*4) = w;
  }
  float e0=0,e1=0,e2=0,e3=0;
  for (int i=beg; i<end; ++i){
    int m = ep[i]; int n = nidx[m];
    float4 g = *(const float4*)(G + (size_t)n*12 + t*4);
    float w0=__expf(g.x-mx0)*inv0, w1=__expf(g.y-mx1)*inv1;
    float w2=__expf(g.z-mx2)*inv2, w3=__expf(g.w-mx3)*inv3;
    const float* vp = Vb + (size_t)n*256;
    e0 += w0*vp[lane]; e1 += w1*vp[64+lane]; e2 += w2*vp[128+lane]; e3 += w3*vp[192+lane];
  }
  float* efp = EF + (size_t)e*256;
  efp[lane]=e0; efp[64+lane]=e1; efp[128+lane]=e2; efp[192+lane]=e3;
}

// ---------------- per-node gather + residual + LayerNorm (wave per node) ----------------
__global__ __launch_bounds__(256) void k_node(const int* __restrict__ noff, const int* __restrict__ np,
    const int* __restrict__ eidx, const float* __restrict__ attn, const float* __restrict__ EF,
    const float* __restrict__ lng, const float* __restrict__ lnb,
    float* __restrict__ hio, bf16* __restrict__ h16,
    void* __restrict__ outv, const int* __restrict__ flag, int last){
  int n = blockIdx.x*4 + (threadIdx.x>>6);
  int lane = threadIdx.x & 63;
  if (n >= N_) return;
  float f0=0,f1=0,f2=0,f3=0;
  int beg = noff[n], end = noff[n+1];
  for (int i=beg; i<end; ++i){
    int m = np[i]; int e = eidx[m];
    float4 w = *(const float4*)(attn + (size_t)m*4);
    const float* ef = EF + (size_t)e*256;
    f0 += w.x*ef[lane]; f1 += w.y*ef[64+lane]; f2 += w.z*ef[128+lane]; f3 += w.w*ef[192+lane];
  }
  const float* hp = hio + (size_t)n*256;
  float h0 = hp[lane]+f0, h1 = hp[64+lane]+f1, h2 = hp[128+lane]+f2, h3 = hp[192+lane]+f3;
  float s = h0+h1+h2+h3;
  #pragma unroll
  for (int d=1; d<64; d<<=1) s += __shfl_xor(s,d,64);
  float mean = s * (1.f/256.f);
  float d0=h0-mean, d1=h1-mean, d2=h2-mean, d3=h3-mean;
  float vv = d0*d0+d1*d1+d2*d2+d3*d3;
  #pragma unroll
  for (int d=1; d<64; d<<=1) vv += __shfl_xor(vv,d,64);
  float rstd = rsqrtf(vv*(1.f/256.f) + 1e-5f);
  float o0 = d0*rstd*lng[lane]     + lnb[lane];
  float o1 = d1*rstd*lng[64+lane]  + lnb[64+lane];
  float o2 = d2*rstd*lng[128+lane] + lnb[128+lane];
  float o3 = d3*rstd*lng[192+lane] + lnb[192+lane];
  if (last){
    if (*flag){
      bf16* op = (bf16*)outv + (size_t)n*256;
      op[lane]=__float2bfloat16(o0); op[64+lane]=__float2bfloat16(o1);
      op[128+lane]=__float2bfloat16(o2); op[192+lane]=__float2bfloat16(o3);
    } else {
      float* op = (float*)outv + (size_t)n*256;
      op[lane]=o0; op[64+lane]=o1; op[128+lane]=o2; op[192+lane]=o3;
    }
  } else {
    float* op = hio + (size_t)n*256;
    op[lane]=o0; op[64+lane]=o1; op[128+lane]=o2; op[192+lane]=o3;
    bf16* o16 = h16 + (size_t)n*256;
    o16[lane]=__float2bfloat16(o0); o16[64+lane]=__float2bfloat16(o1);
    o16[128+lane]=__float2bfloat16(o2); o16[192+lane]=__float2bfloat16(o3);
  }
}

extern "C" void kernel_launch(void* const* d_in, const int* in_sizes, int n_in,
                              void* d_out, int out_size, void* d_ws, size_t ws_size,
                              hipStream_t stream){
  const void* x    = d_in[0];
  const int* ntype = (const int*)d_in[1];
  const int* etype = (const int*)d_in[2];
  const int* nidx  = (const int*)d_in[3];
  const int* eidx  = (const int*)d_in[4];
  (void)in_sizes; (void)n_in; (void)out_size; (void)ws_size;

  char* ws = (char*)d_ws;
  size_t o = 0;
  auto alloc = [&](size_t b)->char*{ char* r = ws + o; o = (o + b + 255) & ~(size_t)255; return r; };
  int*   flag = (int*)  alloc(256);
  float* hbuf = (float*)alloc((size_t)N_*256*4);          // 51.2 MB fp32 hidden state
  float* Vb   = (float*)alloc((size_t)N_*256*4);          // 51.2 MB
  char*  R2   =         alloc((size_t)28000000);          // Hb(25.6M)+S(2.4M), reused as attn+EF
  float* G    = (float*)alloc((size_t)N_*12*4);
  // fp32 weight staging
  float* tq_f  = (float*)alloc(1536*4);
  float* w1_f  = (float*)alloc(81920*4);
  float* b1_f  = (float*)alloc(256*4);
  float* w2_f  = (float*)alloc(256*4);
  float* b2_f  = (float*)alloc(8*4);
  float* wq_f  = (float*)alloc(131072*4);
  float* wv_f  = (float*)alloc(131072*4);
  float* ec_f  = (float*)alloc(1536*4);
  float* lng_f = (float*)alloc(512*4);
  float* lnb_f = (float*)alloc(512*4);
  float* wqe   = (float*)alloc(6144*4);
  float* pre   = (float*)alloc(768*4);
  int* cnt_e  = (int*)alloc((size_t)E_*4);
  int* cnt_n  = (int*)alloc((size_t)N_*4);
  int* eoff   = (int*)alloc((size_t)(E_+1)*4);
  int* noff   = (int*)alloc((size_t)(N_+1)*4);
  int* cur_e  = (int*)alloc((size_t)E_*4);
  int* cur_n  = (int*)alloc((size_t)N_*4);
  int* ep     = (int*)alloc((size_t)M_*4);
  int* np     = (int*)alloc((size_t)M_*4);
  bf16* h16   = (bf16*)alloc((size_t)NPAD_*256*2);        // 25.6 MB bf16 A for MFMA
  bf16* Bp    = (bf16*)alloc((size_t)2*448*256*2);        // 459 KB packed B panels

  float* Hb   = (float*)R2;                                // 25.6 MB
  float* S    = (float*)(R2 + 25600000);                   // 2.4 MB
  float* attn = (float*)R2;                                // 5.12 MB (after gate consumed Hb)
  float* EF   = (float*)(R2 + (size_t)M_*4*4);             // 20.48 MB

  k_sniff<<<1, 256, 0, stream>>>((const unsigned short*)x, flag);
  k_cvt  <<<(N_*256+255)/256, 256, 0, stream>>>(x, hbuf, N_*256, flag);
  k_cvt16<<<(N_*256+255)/256, 256, 0, stream>>>(x, h16, N_*256, flag);
  k_cvt<<<(1536+255)/256,   256, 0, stream>>>(d_in[5],  tq_f,  1536,   flag);
  k_cvt<<<(81920+255)/256,  256, 0, stream>>>(d_in[6],  w1_f,  81920,  flag);
  k_cvt<<<1,                256, 0, stream>>>(d_in[7],  b1_f,  256,    flag);
  k_cvt<<<1,                256, 0, stream>>>(d_in[8],  w2_f,  256,    flag);
  k_cvt<<<1,                256, 0, stream>>>(d_in[9],  b2_f,  8,      flag);
  k_cvt<<<(131072+255)/256, 256, 0, stream>>>(d_in[10], wq_f,  131072, flag);
  k_cvt<<<(131072+255)/256, 256, 0, stream>>>(d_in[11], wv_f,  131072, flag);
  k_cvt<<<(1536+255)/256,   256, 0, stream>>>(d_in[12], ec_f,  1536,   flag);
  k_cvt<<<2,                256, 0, stream>>>(d_in[13], lng_f, 512,    flag);
  k_cvt<<<2,                256, 0, stream>>>(d_in[14], lnb_f, 512,    flag);

  k_zero<<<(E_+255)/256, 256, 0, stream>>>(cnt_e, E_);
  k_zero<<<(N_+255)/256, 256, 0, stream>>>(cnt_n, N_);
  k_hist<<<M_/256, 256, 0, stream>>>(eidx, nidx, cnt_e, cnt_n);
  k_scan<<<1, 1024, 0, stream>>>(cnt_e, eoff, cur_e, E_);
  k_scan<<<1, 1024, 0, stream>>>(cnt_n, noff, cur_n, N_);
  k_fill<<<M_/256, 256, 0, stream>>>(eidx, nidx, cur_e, cur_n, ep, np);
  k_pre<<<3, 256, 0, stream>>>(tq_f, w1_f, b1_f, pre);
  k_wqe<<<24, 256, 0, stream>>>(wq_f, ec_f, wqe);
  k_bpack<<<(2*448*256+255)/256, 256, 0, stream>>>(wv_f, w1_f, wqe, Bp);

  for (int l=0; l<2; ++l){
    k_mgemm<<<dim3(7,391), 256, 0, stream>>>(h16, Bp + (size_t)l*448*256, Vb, Hb, S);
    k_gate<<<12500, 256, 0, stream>>>(Hb, S, pre + l*384, w2_f + l*128, b2_f + l*4, ntype, G);
    k_edge<<<5000, 256, 0, stream>>>(eoff, ep, nidx, etype, G, Vb, attn, EF);
    k_node<<<12500, 256, 0, stream>>>(noff, np, eidx, attn, EF, lng_f + l*256, lnb_f + l*256,
                                      hbuf, h16, d_out, flag, l==1);
  }
}

// Round 5
// 715.138 us; speedup vs baseline: 2.0882x; 1.1266x over previous
//
#include <hip/hip_runtime.h>
#include <hip/hip_bf16.h>

typedef __hip_bfloat16 bf16;
using short8  = __attribute__((ext_vector_type(8))) short;
using float4v = __attribute__((ext_vector_type(4))) float;

static constexpr int N_ = 50000;   // nodes
static constexpr int E_ = 20000;   // hyperedges
static constexpr int M_ = 320000;  // incidence pairs
static constexpr int NPAD_ = 50048;  // 391*128 rows for MFMA grid

__device__ __forceinline__ float b2f(bf16 v){ return __bfloat162float(v); }
__device__ __forceinline__ float sigm(float x){ return 1.f/(1.f+__expf(-x)); }
__device__ __forceinline__ float u2f(unsigned short u){ return __uint_as_float(((unsigned)u)<<16); }
__device__ __forceinline__ unsigned short f2u(float f){ bf16 t=__float2bfloat16(f); return *(unsigned short*)&t; }

// ---------------- dtype sniff: are float tensors stored as bf16 or fp32? ----------------
__global__ __launch_bounds__(256) void k_sniff(const unsigned short* __restrict__ xb, int* flag){
  int tid = threadIdx.x;
  int sane = 0;
  for (int i = tid; i < 4096; i += 256){
    unsigned short u = xb[2*i];
    int ex = (u >> 7) & 0xFF;
    if ((u & 0x7FFF) == 0 || (ex >= 117 && ex <= 137)) sane++;
  }
  #pragma unroll
  for (int d=1; d<64; d<<=1) sane += __shfl_xor(sane, d, 64);
  __shared__ int wsh[4];
  if ((tid&63)==0) wsh[tid>>6] = sane;
  __syncthreads();
  if (tid==0){
    int tot = wsh[0]+wsh[1]+wsh[2]+wsh[3];
    *flag = (tot > 2048) ? 1 : 0;    // 1 = bf16 storage
  }
}

// ---------------- converts ----------------
__global__ __launch_bounds__(256) void k_cvt(const void* __restrict__ src, float* __restrict__ dst,
                                             int n, const int* __restrict__ flag){
  int i = blockIdx.x*256 + threadIdx.x;
  if (i >= n) return;
  if (*flag) dst[i] = b2f(((const bf16*)src)[i]);
  else       dst[i] = ((const float*)src)[i];
}

// x -> hbuf fp32 AND h16 bf16 in one pass
__global__ __launch_bounds__(256) void k_cvtx(const void* __restrict__ src, float* __restrict__ hbuf,
                                              bf16* __restrict__ h16, int n, const int* __restrict__ flag){
  int i = blockIdx.x*256 + threadIdx.x;
  if (i >= n) return;
  if (*flag){ bf16 v = ((const bf16*)src)[i]; h16[i] = v; hbuf[i] = b2f(v); }
  else      { float f = ((const float*)src)[i]; hbuf[i] = f; h16[i] = __float2bfloat16(f); }
}

__global__ __launch_bounds__(256) void k_zero(int* p, int n){
  int i = blockIdx.x*256 + threadIdx.x; if (i<n) p[i]=0;
}

// ---------------- CSR build ----------------
__global__ __launch_bounds__(256) void k_hist(const int* __restrict__ eidx, const int* __restrict__ nidx,
                                              int* cnt_e, int* cnt_n){
  int m = blockIdx.x*256 + threadIdx.x;
  if (m < M_){ atomicAdd(&cnt_e[eidx[m]],1); atomicAdd(&cnt_n[nidx[m]],1); }
}

// hierarchical scan, phase 1: block-local exclusive scan + block sums
__global__ __launch_bounds__(256) void k_scan1(const int* __restrict__ cnt, int* __restrict__ off,
                                               int* __restrict__ bsum, int n){
  int tid = threadIdx.x, lane = tid&63, wid = tid>>6;
  int i = blockIdx.x*256 + tid;
  int v = (i<n)? cnt[i] : 0;
  int s = v;
  #pragma unroll
  for (int d=1; d<64; d<<=1){ int t = __shfl_up(s, d, 64); if (lane>=d) s += t; }
  __shared__ int ws[4]; __shared__ int wo[4];
  if (lane==63) ws[wid] = s;
  __syncthreads();
  if (tid==0){ int a=0; for (int k=0;k<4;k++){ int t=ws[k]; wo[k]=a; a+=t; } bsum[blockIdx.x]=a; }
  __syncthreads();
  if (i<n) off[i] = wo[wid] + s - v;
}

// phase 2: exclusive scan of block sums (nb <= 256) + total into off[n]
__global__ __launch_bounds__(256) void k_scan2(int* __restrict__ bsum, int* __restrict__ off, int nb, int n){
  int tid = threadIdx.x, lane = tid&63, wid = tid>>6;
  int v = (tid<nb)? bsum[tid] : 0;
  int s = v;
  #pragma unroll
  for (int d=1; d<64; d<<=1){ int t = __shfl_up(s, d, 64); if (lane>=d) s += t; }
  __shared__ int ws[4]; __shared__ int wo[4];
  if (lane==63) ws[wid] = s;
  __syncthreads();
  if (tid==0){ int a=0; for (int k=0;k<4;k++){ int t=ws[k]; wo[k]=a; a+=t; } off[n]=a; }
  __syncthreads();
  if (tid<nb) bsum[tid] = wo[wid] + s - v;
}

// phase 3: add block offsets, mirror into cur
__global__ __launch_bounds__(256) void k_scan3(const int* __restrict__ bsum, int* __restrict__ off,
                                               int* __restrict__ cur, int n){
  int i = blockIdx.x*256 + threadIdx.x;
  if (i<n){ int e = off[i] + bsum[blockIdx.x]; off[i]=e; cur[i]=e; }
}

__global__ __launch_bounds__(256) void k_fill(const int* __restrict__ eidx, const int* __restrict__ nidx,
                                              int* cur_e, int* cur_n, int* ep, int* np){
  int m = blockIdx.x*256 + threadIdx.x;
  if (m < M_){
    int p = atomicAdd(&cur_e[eidx[m]],1); ep[p]=m;
    int q = atomicAdd(&cur_n[nidx[m]],1); np[q]=m;
  }
}

// ---------------- pre[l][t][h*32+k] = b1 + sum_d tq[l,h,t,d]*w1[l,h,k,256+d] ----------------
__global__ __launch_bounds__(256) void k_pre(const float* __restrict__ tq, const float* __restrict__ w1,
                                             const float* __restrict__ b1, float* __restrict__ pre){
  int idx = blockIdx.x*256 + threadIdx.x;
  if (idx >= 768) return;
  int l = idx / 384, r = idx % 384;
  int t = r / 128, r2 = r % 128;          // r2 = h*32+k
  int h = r2 >> 5, k = r2 & 31;
  const float* tp = tq + ((l*4+h)*3 + t)*64;
  const float* wp = w1 + (size_t)((l*4+h)*32 + k)*320 + 256;
  float s = b1[(l*4+h)*32 + k];
  for (int d=0; d<64; ++d) s += tp[d]*wp[d];
  pre[(l*3+t)*128 + r2] = s;
}

// ---------------- wqe[l][h*3+t][d] = sum_o ec[l,h,t,o] * wq[l,h,o,d] ----------------
__global__ __launch_bounds__(256) void k_wqe(const float* __restrict__ wq_f, const float* __restrict__ ec_f,
                                             float* __restrict__ wqe){
  int b = blockIdx.x;          // 0..23 = l*12 + h*3 + t
  int l = b/12, ht = b%12, h = ht/3, t = ht%3;
  int d = threadIdx.x;
  const float* ecp = ec_f + ((l*4+h)*3 + t)*64;
  const float* wqp = wq_f + (size_t)((l*4+h)*64)*256;    // [o][d]
  float s = 0.f;
  for (int o=0;o<64;++o) s += ecp[o]*wqp[o*256 + d];
  wqe[(size_t)(l*12+ht)*256 + d] = s;
}

// ---------------- pack B panel: Bp[l][448][256] bf16 = wv | w1[:,:256] | wqe | 0 ----------------
__global__ __launch_bounds__(256) void k_bpack(const float* __restrict__ wv_f, const float* __restrict__ w1_f,
                                               const float* __restrict__ wqe, bf16* __restrict__ Bp){
  int idx = blockIdx.x*256 + threadIdx.x;
  if (idx >= 2*448*256) return;
  int l = idx / (448*256), r = idx % (448*256);
  int c = r >> 8, k = r & 255;
  float v = 0.f;
  if (c < 256)      v = wv_f[(size_t)l*65536 + (size_t)c*256 + k];
  else if (c < 384) v = w1_f[(size_t)l*40960 + (size_t)(c-256)*320 + k];
  else if (c < 396) v = wqe[(size_t)(l*12 + c-384)*256 + k];
  Bp[idx] = __float2bfloat16(v);
}

// ---------------- MFMA GEMM: [NPAD,256]bf16 x [256,448]bf16 -> V16(interleaved bf16)|Hgate|S ----------------
// grid (7, 391), block 256 = 4 waves; wave owns 32 rows (2 m-tiles), block owns 64 cols (4 n-tiles).
// V cols (<256) go to V16 in head-interleaved layout [n][d=0..63][h=0..3] bf16.
__global__ __launch_bounds__(256) void k_mgemm(const bf16* __restrict__ A16, const bf16* __restrict__ Bp,
    bf16* __restrict__ V16, float* __restrict__ Hb, float* __restrict__ S){
  int wid = threadIdx.x >> 6, lane = threadIdx.x & 63;
  int q = lane >> 4, li = lane & 15;
  int row0 = blockIdx.y*128 + wid*32;
  int col0 = blockIdx.x*64;
  float4v acc[2][4];
  #pragma unroll
  for (int i=0;i<2;i++)
    #pragma unroll
    for (int j=0;j<4;j++) acc[i][j] = (float4v)(0.f);
  const bf16* a0p = A16 + (size_t)(row0 + li)*256;
  const bf16* a1p = A16 + (size_t)(row0 + 16 + li)*256;
  const bf16* bp  = Bp  + (size_t)(col0 + li)*256;
  #pragma unroll
  for (int kc=0; kc<256; kc+=32){
    int ko = kc + q*8;
    short8 a0 = *(const short8*)(a0p + ko);
    short8 a1 = *(const short8*)(a1p + ko);
    short8 b0 = *(const short8*)(bp + ko);
    short8 b1 = *(const short8*)(bp + 16*256 + ko);
    short8 b2 = *(const short8*)(bp + 32*256 + ko);
    short8 b3 = *(const short8*)(bp + 48*256 + ko);
    acc[0][0] = __builtin_amdgcn_mfma_f32_16x16x32_bf16(a0,b0,acc[0][0],0,0,0);
    acc[0][1] = __builtin_amdgcn_mfma_f32_16x16x32_bf16(a0,b1,acc[0][1],0,0,0);
    acc[0][2] = __builtin_amdgcn_mfma_f32_16x16x32_bf16(a0,b2,acc[0][2],0,0,0);
    acc[0][3] = __builtin_amdgcn_mfma_f32_16x16x32_bf16(a0,b3,acc[0][3],0,0,0);
    acc[1][0] = __builtin_amdgcn_mfma_f32_16x16x32_bf16(a1,b0,acc[1][0],0,0,0);
    acc[1][1] = __builtin_amdgcn_mfma_f32_16x16x32_bf16(a1,b1,acc[1][1],0,0,0);
    acc[1][2] = __builtin_amdgcn_mfma_f32_16x16x32_bf16(a1,b2,acc[1][2],0,0,0);
    acc[1][3] = __builtin_amdgcn_mfma_f32_16x16x32_bf16(a1,b3,acc[1][3],0,0,0);
  }
  // D layout: row = quad*4 + reg, col = lane&15  [m89/m91 verified]
  #pragma unroll
  for (int i=0;i<2;i++){
    #pragma unroll
    for (int r=0;r<4;r++){
      int grow = row0 + i*16 + q*4 + r;
      if (grow >= N_) continue;
      #pragma unroll
      for (int j=0;j<4;j++){
        int gc = col0 + j*16 + li;
        float v = acc[i][j][r];
        if (gc < 256)      V16[(size_t)grow*256 + (gc&63)*4 + (gc>>6)] = __float2bfloat16(v);
        else if (gc < 384) Hb[(size_t)grow*128 + gc - 256] = v;
        else if (gc < 396) S [(size_t)grow*12  + gc - 384] = v;
      }
    }
  }
}

// ---------------- per-node gate: G[n,t,h] = lrelu(S[n,h,t]) * sigmoid(gate[n,h]) ----------------
__global__ __launch_bounds__(256) void k_gate(const float* __restrict__ Hb, const float* __restrict__ S,
    const float* __restrict__ pre_l, const float* __restrict__ w2_l, const float* __restrict__ b2_l,
    const int* __restrict__ ntype, float* __restrict__ G){
  int node = blockIdx.x*4 + (threadIdx.x>>6);
  int lane = threadIdx.x & 63;
  if (node >= N_) return;
  int typ = ntype[node];
  const float* pr = pre_l + typ*128;
  float v0 = tanhf(Hb[(size_t)node*128 + lane]      + pr[lane]);
  float v1 = tanhf(Hb[(size_t)node*128 + 64 + lane] + pr[64+lane]);
  float p0 = v0 * w2_l[lane];
  float p1 = v1 * w2_l[64+lane];
  #pragma unroll
  for (int d=1; d<32; d<<=1){ p0 += __shfl_xor(p0,d,64); p1 += __shfl_xor(p1,d,64); }
  float at0 = sigm(__shfl(p0, 0,64) + b2_l[0]);
  float at1 = sigm(__shfl(p0,32,64) + b2_l[1]);
  float at2 = sigm(__shfl(p1, 0,64) + b2_l[2]);
  float at3 = sigm(__shfl(p1,32,64) + b2_l[3]);
  if (lane < 12){
    int h = lane / 3, t = lane % 3;       // S col order = h*3+t
    float sv = S[(size_t)node*12 + lane];
    float lr = (sv > 0.f) ? sv : 0.2f*sv;
    float av = (h==0)? at0 : (h==1)? at1 : (h==2)? at2 : at3;
    G[(size_t)node*12 + t*4 + h] = lr * av;   // G layout: [n][t][4 heads]
  }
}

// ---------------- per-edge softmax + edge_feat (wave per edge, no atomics) ----------------
__global__ __launch_bounds__(256) void k_edge(const int* __restrict__ eoff, const int* __restrict__ ep,
    const int* __restrict__ nidx, const int* __restrict__ etype,
    const float* __restrict__ G, const unsigned short* __restrict__ V16,
    float* __restrict__ attn, unsigned short* __restrict__ EF16){
  int e = blockIdx.x*4 + (threadIdx.x>>6);
  int lane = threadIdx.x & 63;
  if (e >= E_) return;
  int beg = eoff[e], end = eoff[e+1];
  if (beg == end) return;
  int t = etype[e];
  float mx0=-1e30f, mx1=-1e30f, mx2=-1e30f, mx3=-1e30f;
  for (int i=beg+lane; i<end; i+=64){
    int m = ep[i]; int n = nidx[m];
    float4 g = *(const float4*)(G + (size_t)n*12 + t*4);
    mx0=fmaxf(mx0,g.x); mx1=fmaxf(mx1,g.y); mx2=fmaxf(mx2,g.z); mx3=fmaxf(mx3,g.w);
  }
  #pragma unroll
  for (int d=1; d<64; d<<=1){
    mx0=fmaxf(mx0,__shfl_xor(mx0,d,64)); mx1=fmaxf(mx1,__shfl_xor(mx1,d,64));
    mx2=fmaxf(mx2,__shfl_xor(mx2,d,64)); mx3=fmaxf(mx3,__shfl_xor(mx3,d,64));
  }
  float sm0=0,sm1=0,sm2=0,sm3=0;
  for (int i=beg+lane; i<end; i+=64){
    int m = ep[i]; int n = nidx[m];
    float4 g = *(const float4*)(G + (size_t)n*12 + t*4);
    sm0+=__expf(g.x-mx0); sm1+=__expf(g.y-mx1); sm2+=__expf(g.z-mx2); sm3+=__expf(g.w-mx3);
  }
  #pragma unroll
  for (int d=1; d<64; d<<=1){
    sm0+=__shfl_xor(sm0,d,64); sm1+=__shfl_xor(sm1,d,64);
    sm2+=__shfl_xor(sm2,d,64); sm3+=__shfl_xor(sm3,d,64);
  }
  float inv0=1.f/sm0, inv1=1.f/sm1, inv2=1.f/sm2, inv3=1.f/sm3;
  for (int i=beg+lane; i<end; i+=64){
    int m = ep[i]; int n = nidx[m];
    float4 g = *(const float4*)(G + (size_t)n*12 + t*4);
    float4 w;
    w.x=__expf(g.x-mx0)*inv0; w.y=__expf(g.y-mx1)*inv1;
    w.z=__expf(g.z-mx2)*inv2; w.w=__expf(g.w-mx3)*inv3;
    *(float4*)(attn + (size_t)m*4) = w;
  }
  // edge_feat accumulate: lane = head-dim; V16 interleaved [n][d][h] -> one ushort4 per lane
  float e0=0,e1=0,e2=0,e3=0;
  for (int i=beg; i<end; ++i){
    int m = ep[i]; int n = nidx[m];
    float4 g = *(const float4*)(G + (size_t)n*12 + t*4);
    float w0=__expf(g.x-mx0)*inv0, w1=__expf(g.y-mx1)*inv1;
    float w2=__expf(g.z-mx2)*inv2, w3=__expf(g.w-mx3)*inv3;
    ushort4 v = *(const ushort4*)(V16 + (size_t)n*256 + lane*4);
    e0 += w0*u2f(v.x); e1 += w1*u2f(v.y); e2 += w2*u2f(v.z); e3 += w3*u2f(v.w);
  }
  ushort4 ev; ev.x=f2u(e0); ev.y=f2u(e1); ev.z=f2u(e2); ev.w=f2u(e3);
  *(ushort4*)(EF16 + (size_t)e*256 + lane*4) = ev;
}

// ---------------- per-node gather + residual + LayerNorm (wave per node) ----------------
__global__ __launch_bounds__(256) void k_node(const int* __restrict__ noff, const int* __restrict__ np,
    const int* __restrict__ eidx, const float* __restrict__ attn, const unsigned short* __restrict__ EF16,
    const float* __restrict__ lng, const float* __restrict__ lnb,
    float* __restrict__ hio, bf16* __restrict__ h16,
    void* __restrict__ outv, const int* __restrict__ flag, int last){
  int n = blockIdx.x*4 + (threadIdx.x>>6);
  int lane = threadIdx.x & 63;
  if (n >= N_) return;
  float f0=0,f1=0,f2=0,f3=0;
  int beg = noff[n], end = noff[n+1];
  for (int i=beg; i<end; ++i){
    int m = np[i]; int e = eidx[m];
    float4 w = *(const float4*)(attn + (size_t)m*4);
    ushort4 v = *(const ushort4*)(EF16 + (size_t)e*256 + lane*4);
    f0 += w.x*u2f(v.x); f1 += w.y*u2f(v.y); f2 += w.z*u2f(v.z); f3 += w.w*u2f(v.w);
  }
  const float* hp = hio + (size_t)n*256;
  float h0 = hp[lane]+f0, h1 = hp[64+lane]+f1, h2 = hp[128+lane]+f2, h3 = hp[192+lane]+f3;
  float s = h0+h1+h2+h3;
  #pragma unroll
  for (int d=1; d<64; d<<=1) s += __shfl_xor(s,d,64);
  float mean = s * (1.f/256.f);
  float d0=h0-mean, d1=h1-mean, d2=h2-mean, d3=h3-mean;
  float vv = d0*d0+d1*d1+d2*d2+d3*d3;
  #pragma unroll
  for (int d=1; d<64; d<<=1) vv += __shfl_xor(vv,d,64);
  float rstd = rsqrtf(vv*(1.f/256.f) + 1e-5f);
  float o0 = d0*rstd*lng[lane]     + lnb[lane];
  float o1 = d1*rstd*lng[64+lane]  + lnb[64+lane];
  float o2 = d2*rstd*lng[128+lane] + lnb[128+lane];
  float o3 = d3*rstd*lng[192+lane] + lnb[192+lane];
  if (last){
    if (*flag){
      bf16* op = (bf16*)outv + (size_t)n*256;
      op[lane]=__float2bfloat16(o0); op[64+lane]=__float2bfloat16(o1);
      op[128+lane]=__float2bfloat16(o2); op[192+lane]=__float2bfloat16(o3);
    } else {
      float* op = (float*)outv + (size_t)n*256;
      op[lane]=o0; op[64+lane]=o1; op[128+lane]=o2; op[192+lane]=o3;
    }
  } else {
    float* op = hio + (size_t)n*256;
    op[lane]=o0; op[64+lane]=o1; op[128+lane]=o2; op[192+lane]=o3;
    bf16* o16 = h16 + (size_t)n*256;
    o16[lane]=__float2bfloat16(o0); o16[64+lane]=__float2bfloat16(o1);
    o16[128+lane]=__float2bfloat16(o2); o16[192+lane]=__float2bfloat16(o3);
  }
}

extern "C" void kernel_launch(void* const* d_in, const int* in_sizes, int n_in,
                              void* d_out, int out_size, void* d_ws, size_t ws_size,
                              hipStream_t stream){
  const void* x    = d_in[0];
  const int* ntype = (const int*)d_in[1];
  const int* etype = (const int*)d_in[2];
  const int* nidx  = (const int*)d_in[3];
  const int* eidx  = (const int*)d_in[4];
  (void)in_sizes; (void)n_in; (void)out_size; (void)ws_size;

  char* ws = (char*)d_ws;
  size_t o = 0;
  auto alloc = [&](size_t b)->char*{ char* r = ws + o; o = (o + b + 255) & ~(size_t)255; return r; };
  int*   flag = (int*)  alloc(256);
  float* hbuf = (float*)alloc((size_t)N_*256*4);          // 51.2 MB fp32 hidden state
  char*  R2   =         alloc((size_t)28000000);          // Hb+S during gemm/gate; attn+EF16 during edge/node
  float* G    = (float*)alloc((size_t)N_*12*4);
  // fp32 weight staging
  float* tq_f  = (float*)alloc(1536*4);
  float* w1_f  = (float*)alloc(81920*4);
  float* b1_f  = (float*)alloc(256*4);
  float* w2_f  = (float*)alloc(256*4);
  float* b2_f  = (float*)alloc(8*4);
  float* wq_f  = (float*)alloc(131072*4);
  float* wv_f  = (float*)alloc(131072*4);
  float* ec_f  = (float*)alloc(1536*4);
  float* lng_f = (float*)alloc(512*4);
  float* lnb_f = (float*)alloc(512*4);
  float* wqe   = (float*)alloc(6144*4);
  float* pre   = (float*)alloc(768*4);
  int* cnt_e  = (int*)alloc((size_t)E_*4);
  int* cnt_n  = (int*)alloc((size_t)N_*4);
  int* eoff   = (int*)alloc((size_t)(E_+1)*4);
  int* noff   = (int*)alloc((size_t)(N_+1)*4);
  int* cur_e  = (int*)alloc((size_t)E_*4);
  int* cur_n  = (int*)alloc((size_t)N_*4);
  int* ep     = (int*)alloc((size_t)M_*4);
  int* np     = (int*)alloc((size_t)M_*4);
  int* bsum   = (int*)alloc(256*4);
  bf16* h16   = (bf16*)alloc((size_t)NPAD_*256*2);        // 25.6 MB bf16 A for MFMA
  bf16* Bp    = (bf16*)alloc((size_t)2*448*256*2);        // 459 KB packed B panels
  bf16* V16   = (bf16*)alloc((size_t)N_*256*2);           // 25.6 MB interleaved [n][d][h]

  float* Hb   = (float*)R2;                                // 25.6 MB (gemm->gate)
  float* S    = (float*)(R2 + 25600000);                   // 2.4 MB  (gemm->gate)
  float* attn = (float*)R2;                                // 5.12 MB (edge->node)
  unsigned short* EF16 = (unsigned short*)(R2 + (size_t)M_*4*4);  // 10.24 MB (edge->node)

  const int NB_E = (E_+255)/256, NB_N = (N_+255)/256;

  k_sniff<<<1, 256, 0, stream>>>((const unsigned short*)x, flag);
  k_cvtx <<<(N_*256+255)/256, 256, 0, stream>>>(x, hbuf, h16, N_*256, flag);
  k_cvt<<<(1536+255)/256,   256, 0, stream>>>(d_in[5],  tq_f,  1536,   flag);
  k_cvt<<<(81920+255)/256,  256, 0, stream>>>(d_in[6],  w1_f,  81920,  flag);
  k_cvt<<<1,                256, 0, stream>>>(d_in[7],  b1_f,  256,    flag);
  k_cvt<<<1,                256, 0, stream>>>(d_in[8],  w2_f,  256,    flag);
  k_cvt<<<1,                256, 0, stream>>>(d_in[9],  b2_f,  8,      flag);
  k_cvt<<<(131072+255)/256, 256, 0, stream>>>(d_in[10], wq_f,  131072, flag);
  k_cvt<<<(131072+255)/256, 256, 0, stream>>>(d_in[11], wv_f,  131072, flag);
  k_cvt<<<(1536+255)/256,   256, 0, stream>>>(d_in[12], ec_f,  1536,   flag);
  k_cvt<<<2,                256, 0, stream>>>(d_in[13], lng_f, 512,    flag);
  k_cvt<<<2,                256, 0, stream>>>(d_in[14], lnb_f, 512,    flag);

  k_zero<<<NB_E, 256, 0, stream>>>(cnt_e, E_);
  k_zero<<<NB_N, 256, 0, stream>>>(cnt_n, N_);
  k_hist<<<M_/256, 256, 0, stream>>>(eidx, nidx, cnt_e, cnt_n);
  k_scan1<<<NB_E, 256, 0, stream>>>(cnt_e, eoff, bsum, E_);
  k_scan2<<<1, 256, 0, stream>>>(bsum, eoff, NB_E, E_);
  k_scan3<<<NB_E, 256, 0, stream>>>(bsum, eoff, cur_e, E_);
  k_scan1<<<NB_N, 256, 0, stream>>>(cnt_n, noff, bsum, N_);
  k_scan2<<<1, 256, 0, stream>>>(bsum, noff, NB_N, N_);
  k_scan3<<<NB_N, 256, 0, stream>>>(bsum, noff, cur_n, N_);
  k_fill<<<M_/256, 256, 0, stream>>>(eidx, nidx, cur_e, cur_n, ep, np);
  k_pre<<<3, 256, 0, stream>>>(tq_f, w1_f, b1_f, pre);
  k_wqe<<<24, 256, 0, stream>>>(wq_f, ec_f, wqe);
  k_bpack<<<(2*448*256+255)/256, 256, 0, stream>>>(wv_f, w1_f, wqe, Bp);

  for (int l=0; l<2; ++l){
    k_mgemm<<<dim3(7,391), 256, 0, stream>>>(h16, Bp + (size_t)l*448*256, V16, Hb, S);
    k_gate<<<12500, 256, 0, stream>>>(Hb, S, pre + l*384, w2_f + l*128, b2_f + l*4, ntype, G);
    k_edge<<<5000, 256, 0, stream>>>(eoff, ep, nidx, etype, G, (const unsigned short*)V16, attn, EF16);
    k_node<<<12500, 256, 0, stream>>>(noff, np, eidx, attn, EF16, lng_f + l*256, lnb_f + l*256,
                                      hbuf, h16, d_out, flag, l==1);
  }
}

// Round 6
// 584.023 us; speedup vs baseline: 2.5570x; 1.2245x over previous
//
#include <hip/hip_runtime.h>
#include <hip/hip_bf16.h>

typedef __hip_bfloat16 bf16;
using short8  = __attribute__((ext_vector_type(8))) short;
using float4v = __attribute__((ext_vector_type(4))) float;

static constexpr int N_ = 50000;   // nodes
static constexpr int E_ = 20000;   // hyperedges
static constexpr int M_ = 320000;  // incidence pairs
static constexpr int NPAD_ = 50048;  // 391*128 rows for MFMA grid

__device__ __forceinline__ float b2f(bf16 v){ return __bfloat162float(v); }
__device__ __forceinline__ float sigm(float x){ return 1.f/(1.f+__expf(-x)); }
__device__ __forceinline__ float u2f(unsigned short u){ return __uint_as_float(((unsigned)u)<<16); }
__device__ __forceinline__ unsigned short f2u(float f){ bf16 t=__float2bfloat16(f); return *(unsigned short*)&t; }

// ---------------- dtype sniff ----------------
__global__ __launch_bounds__(256) void k_sniff(const unsigned short* __restrict__ xb, int* flag){
  int tid = threadIdx.x;
  int sane = 0;
  for (int i = tid; i < 4096; i += 256){
    unsigned short u = xb[2*i];
    int ex = (u >> 7) & 0xFF;
    if ((u & 0x7FFF) == 0 || (ex >= 117 && ex <= 137)) sane++;
  }
  #pragma unroll
  for (int d=1; d<64; d<<=1) sane += __shfl_xor(sane, d, 64);
  __shared__ int wsh[4];
  if ((tid&63)==0) wsh[tid>>6] = sane;
  __syncthreads();
  if (tid==0){
    int tot = wsh[0]+wsh[1]+wsh[2]+wsh[3];
    *flag = (tot > 2048) ? 1 : 0;    // 1 = bf16 storage
  }
}

// ---------------- converts ----------------
__global__ __launch_bounds__(256) void k_cvt(const void* __restrict__ src, float* __restrict__ dst,
                                             int n, const int* __restrict__ flag){
  int i = blockIdx.x*256 + threadIdx.x;
  if (i >= n) return;
  if (*flag) dst[i] = b2f(((const bf16*)src)[i]);
  else       dst[i] = ((const float*)src)[i];
}

__global__ __launch_bounds__(256) void k_cvt16(const void* __restrict__ src, bf16* __restrict__ dst,
                                               int n, const int* __restrict__ flag){
  int i = blockIdx.x*256 + threadIdx.x;
  if (i >= n) return;
  if (*flag) dst[i] = ((const bf16*)src)[i];
  else       dst[i] = __float2bfloat16(((const float*)src)[i]);
}

__global__ __launch_bounds__(256) void k_zero(int* p, int n){
  int i = blockIdx.x*256 + threadIdx.x; if (i<n) p[i]=0;
}

// ---------------- CSR build ----------------
__global__ __launch_bounds__(256) void k_hist(const int* __restrict__ eidx, const int* __restrict__ nidx,
                                              int* cnt_e, int* cnt_n){
  int m = blockIdx.x*256 + threadIdx.x;
  if (m < M_){ atomicAdd(&cnt_e[eidx[m]],1); atomicAdd(&cnt_n[nidx[m]],1); }
}

__global__ __launch_bounds__(256) void k_scan1(const int* __restrict__ cnt, int* __restrict__ off,
                                               int* __restrict__ bsum, int n){
  int tid = threadIdx.x, lane = tid&63, wid = tid>>6;
  int i = blockIdx.x*256 + tid;
  int v = (i<n)? cnt[i] : 0;
  int s = v;
  #pragma unroll
  for (int d=1; d<64; d<<=1){ int t = __shfl_up(s, d, 64); if (lane>=d) s += t; }
  __shared__ int ws[4]; __shared__ int wo[4];
  if (lane==63) ws[wid] = s;
  __syncthreads();
  if (tid==0){ int a=0; for (int k=0;k<4;k++){ int t=ws[k]; wo[k]=a; a+=t; } bsum[blockIdx.x]=a; }
  __syncthreads();
  if (i<n) off[i] = wo[wid] + s - v;
}

__global__ __launch_bounds__(256) void k_scan2(int* __restrict__ bsum, int* __restrict__ off, int nb, int n){
  int tid = threadIdx.x, lane = tid&63, wid = tid>>6;
  int v = (tid<nb)? bsum[tid] : 0;
  int s = v;
  #pragma unroll
  for (int d=1; d<64; d<<=1){ int t = __shfl_up(s, d, 64); if (lane>=d) s += t; }
  __shared__ int ws[4]; __shared__ int wo[4];
  if (lane==63) ws[wid] = s;
  __syncthreads();
  if (tid==0){ int a=0; for (int k=0;k<4;k++){ int t=ws[k]; wo[k]=a; a+=t; } off[n]=a; }
  __syncthreads();
  if (tid<nb) bsum[tid] = wo[wid] + s - v;
}

__global__ __launch_bounds__(256) void k_scan3(const int* __restrict__ bsum, int* __restrict__ off,
                                               int* __restrict__ cur, int n){
  int i = blockIdx.x*256 + threadIdx.x;
  if (i<n){ int e = off[i] + bsum[blockIdx.x]; off[i]=e; cur[i]=e; }
}

__global__ __launch_bounds__(256) void k_fill(const int* __restrict__ eidx, const int* __restrict__ nidx,
                                              int* cur_e, int* cur_n, int* ep, int* np){
  int m = blockIdx.x*256 + threadIdx.x;
  if (m < M_){
    int p = atomicAdd(&cur_e[eidx[m]],1); ep[p]=m;
    int q = atomicAdd(&cur_n[nidx[m]],1); np[q]=m;
  }
}

// ---------------- pre / wqe / bpack ----------------
__global__ __launch_bounds__(256) void k_pre(const float* __restrict__ tq, const float* __restrict__ w1,
                                             const float* __restrict__ b1, float* __restrict__ pre){
  int idx = blockIdx.x*256 + threadIdx.x;
  if (idx >= 768) return;
  int l = idx / 384, r = idx % 384;
  int t = r / 128, r2 = r % 128;
  int h = r2 >> 5, k = r2 & 31;
  const float* tp = tq + ((l*4+h)*3 + t)*64;
  const float* wp = w1 + (size_t)((l*4+h)*32 + k)*320 + 256;
  float s = b1[(l*4+h)*32 + k];
  for (int d=0; d<64; ++d) s += tp[d]*wp[d];
  pre[(l*3+t)*128 + r2] = s;
}

__global__ __launch_bounds__(256) void k_wqe(const float* __restrict__ wq_f, const float* __restrict__ ec_f,
                                             float* __restrict__ wqe){
  int b = blockIdx.x;
  int l = b/12, ht = b%12, h = ht/3, t = ht%3;
  int d = threadIdx.x;
  const float* ecp = ec_f + ((l*4+h)*3 + t)*64;
  const float* wqp = wq_f + (size_t)((l*4+h)*64)*256;
  float s = 0.f;
  for (int o=0;o<64;++o) s += ecp[o]*wqp[o*256 + d];
  wqe[(size_t)(l*12+ht)*256 + d] = s;
}

__global__ __launch_bounds__(256) void k_bpack(const float* __restrict__ wv_f, const float* __restrict__ w1_f,
                                               const float* __restrict__ wqe, bf16* __restrict__ Bp){
  int idx = blockIdx.x*256 + threadIdx.x;
  if (idx >= 2*448*256) return;
  int l = idx / (448*256), r = idx % (448*256);
  int c = r >> 8, k = r & 255;
  float v = 0.f;
  if (c < 256)      v = wv_f[(size_t)l*65536 + (size_t)c*256 + k];
  else if (c < 384) v = w1_f[(size_t)l*40960 + (size_t)(c-256)*320 + k];
  else if (c < 396) v = wqe[(size_t)(l*12 + c-384)*256 + k];
  Bp[idx] = __float2bfloat16(v);
}

// ---------------- MFMA GEMM ----------------
__global__ __launch_bounds__(256) void k_mgemm(const bf16* __restrict__ A16, const bf16* __restrict__ Bp,
    bf16* __restrict__ V16, float* __restrict__ Hb, float* __restrict__ S){
  int wid = threadIdx.x >> 6, lane = threadIdx.x & 63;
  int q = lane >> 4, li = lane & 15;
  int row0 = blockIdx.y*128 + wid*32;
  int col0 = blockIdx.x*64;
  float4v acc[2][4];
  #pragma unroll
  for (int i=0;i<2;i++)
    #pragma unroll
    for (int j=0;j<4;j++) acc[i][j] = (float4v)(0.f);
  const bf16* a0p = A16 + (size_t)(row0 + li)*256;
  const bf16* a1p = A16 + (size_t)(row0 + 16 + li)*256;
  const bf16* bp  = Bp  + (size_t)(col0 + li)*256;
  #pragma unroll
  for (int kc=0; kc<256; kc+=32){
    int ko = kc + q*8;
    short8 a0 = *(const short8*)(a0p + ko);
    short8 a1 = *(const short8*)(a1p + ko);
    short8 b0 = *(const short8*)(bp + ko);
    short8 b1 = *(const short8*)(bp + 16*256 + ko);
    short8 b2 = *(const short8*)(bp + 32*256 + ko);
    short8 b3 = *(const short8*)(bp + 48*256 + ko);
    acc[0][0] = __builtin_amdgcn_mfma_f32_16x16x32_bf16(a0,b0,acc[0][0],0,0,0);
    acc[0][1] = __builtin_amdgcn_mfma_f32_16x16x32_bf16(a0,b1,acc[0][1],0,0,0);
    acc[0][2] = __builtin_amdgcn_mfma_f32_16x16x32_bf16(a0,b2,acc[0][2],0,0,0);
    acc[0][3] = __builtin_amdgcn_mfma_f32_16x16x32_bf16(a0,b3,acc[0][3],0,0,0);
    acc[1][0] = __builtin_amdgcn_mfma_f32_16x16x32_bf16(a1,b0,acc[1][0],0,0,0);
    acc[1][1] = __builtin_amdgcn_mfma_f32_16x16x32_bf16(a1,b1,acc[1][1],0,0,0);
    acc[1][2] = __builtin_amdgcn_mfma_f32_16x16x32_bf16(a1,b2,acc[1][2],0,0,0);
    acc[1][3] = __builtin_amdgcn_mfma_f32_16x16x32_bf16(a1,b3,acc[1][3],0,0,0);
  }
  #pragma unroll
  for (int i=0;i<2;i++){
    #pragma unroll
    for (int r=0;r<4;r++){
      int grow = row0 + i*16 + q*4 + r;
      if (grow >= N_) continue;
      #pragma unroll
      for (int j=0;j<4;j++){
        int gc = col0 + j*16 + li;
        float v = acc[i][j][r];
        if (gc < 256)      V16[(size_t)grow*256 + (gc&63)*4 + (gc>>6)] = __float2bfloat16(v);
        else if (gc < 384) Hb[(size_t)grow*128 + gc - 256] = v;
        else if (gc < 396) S [(size_t)grow*12  + gc - 384] = v;
      }
    }
  }
}

// ---------------- per-node gate ----------------
__global__ __launch_bounds__(256) void k_gate(const float* __restrict__ Hb, const float* __restrict__ S,
    const float* __restrict__ pre_l, const float* __restrict__ w2_l, const float* __restrict__ b2_l,
    const int* __restrict__ ntype, float* __restrict__ G){
  int node = blockIdx.x*4 + (threadIdx.x>>6);
  int lane = threadIdx.x & 63;
  if (node >= N_) return;
  int typ = ntype[node];
  const float* pr = pre_l + typ*128;
  float v0 = tanhf(Hb[(size_t)node*128 + lane]      + pr[lane]);
  float v1 = tanhf(Hb[(size_t)node*128 + 64 + lane] + pr[64+lane]);
  float p0 = v0 * w2_l[lane];
  float p1 = v1 * w2_l[64+lane];
  #pragma unroll
  for (int d=1; d<32; d<<=1){ p0 += __shfl_xor(p0,d,64); p1 += __shfl_xor(p1,d,64); }
  float at0 = sigm(__shfl(p0, 0,64) + b2_l[0]);
  float at1 = sigm(__shfl(p0,32,64) + b2_l[1]);
  float at2 = sigm(__shfl(p1, 0,64) + b2_l[2]);
  float at3 = sigm(__shfl(p1,32,64) + b2_l[3]);
  if (lane < 12){
    int h = lane / 3, t = lane % 3;
    float sv = S[(size_t)node*12 + lane];
    float lr = (sv > 0.f) ? sv : 0.2f*sv;
    float av = (h==0)? at0 : (h==1)? at1 : (h==2)? at2 : at3;
    G[(size_t)node*12 + t*4 + h] = lr * av;
  }
}

// ---------------- per-edge softmax + edge_feat (single-pass, pipelined gather) ----------------
__global__ __launch_bounds__(256) void k_edge(const int* __restrict__ eoff, const int* __restrict__ ep,
    const int* __restrict__ nidx, const int* __restrict__ etype,
    const float* __restrict__ G, const unsigned short* __restrict__ V16,
    float* __restrict__ attn, unsigned short* __restrict__ EF16){
  int e = blockIdx.x*4 + (threadIdx.x>>6);
  int lane = threadIdx.x & 63;
  if (e >= E_) return;
  int beg = eoff[e], end = eoff[e+1];
  int deg = end - beg;
  if (deg == 0) return;
  int t = etype[e];
  float a0=0,a1=0,a2=0,a3=0;

  if (deg <= 64){
    // lane = pair; everything register-resident
    int i = beg + lane;
    int m = -1, n = 0;
    float4 g; g.x=g.y=g.z=g.w=-1e30f;
    if (lane < deg){
      m = ep[i]; n = nidx[m];
      g = *(const float4*)(G + (size_t)n*12 + t*4);
    }
    float mx0=g.x, mx1=g.y, mx2=g.z, mx3=g.w;
    #pragma unroll
    for (int d=1; d<64; d<<=1){
      mx0=fmaxf(mx0,__shfl_xor(mx0,d,64)); mx1=fmaxf(mx1,__shfl_xor(mx1,d,64));
      mx2=fmaxf(mx2,__shfl_xor(mx2,d,64)); mx3=fmaxf(mx3,__shfl_xor(mx3,d,64));
    }
    float ex0=0,ex1=0,ex2=0,ex3=0;
    if (lane < deg){
      ex0=__expf(g.x-mx0); ex1=__expf(g.y-mx1); ex2=__expf(g.z-mx2); ex3=__expf(g.w-mx3);
    }
    float s0=ex0,s1=ex1,s2=ex2,s3=ex3;
    #pragma unroll
    for (int d=1; d<64; d<<=1){
      s0+=__shfl_xor(s0,d,64); s1+=__shfl_xor(s1,d,64);
      s2+=__shfl_xor(s2,d,64); s3+=__shfl_xor(s3,d,64);
    }
    float4 w; w.x=ex0/s0; w.y=ex1/s1; w.z=ex2/s2; w.w=ex3/s3;
    if (lane < deg) *(float4*)(attn + (size_t)m*4) = w;
    // pipelined serial gather: addresses from registers via shfl, depth 4
    auto ldrow = [&](int j)->ushort4{
      int nn = __shfl(n, j, 64);
      return *(const ushort4*)(V16 + (size_t)nn*256 + (lane<<2));
    };
    ushort4 v0v,v1v,v2v,v3v;
    if (deg>0) v0v=ldrow(0);
    if (deg>1) v1v=ldrow(1);
    if (deg>2) v2v=ldrow(2);
    if (deg>3) v3v=ldrow(3);
    for (int j=0;j<deg;j+=4){
      { float wx=__shfl(w.x,j,64),wy=__shfl(w.y,j,64),wz=__shfl(w.z,j,64),wq=__shfl(w.w,j,64);
        a0+=wx*u2f(v0v.x); a1+=wy*u2f(v0v.y); a2+=wz*u2f(v0v.z); a3+=wq*u2f(v0v.w);
        if (j+4<deg) v0v=ldrow(j+4); }
      if (j+1<deg){
        float wx=__shfl(w.x,j+1,64),wy=__shfl(w.y,j+1,64),wz=__shfl(w.z,j+1,64),wq=__shfl(w.w,j+1,64);
        a0+=wx*u2f(v1v.x); a1+=wy*u2f(v1v.y); a2+=wz*u2f(v1v.z); a3+=wq*u2f(v1v.w);
        if (j+5<deg) v1v=ldrow(j+5); }
      if (j+2<deg){
        float wx=__shfl(w.x,j+2,64),wy=__shfl(w.y,j+2,64),wz=__shfl(w.z,j+2,64),wq=__shfl(w.w,j+2,64);
        a0+=wx*u2f(v2v.x); a1+=wy*u2f(v2v.y); a2+=wz*u2f(v2v.z); a3+=wq*u2f(v2v.w);
        if (j+6<deg) v2v=ldrow(j+6); }
      if (j+3<deg){
        float wx=__shfl(w.x,j+3,64),wy=__shfl(w.y,j+3,64),wz=__shfl(w.z,j+3,64),wq=__shfl(w.w,j+3,64);
        a0+=wx*u2f(v3v.x); a1+=wy*u2f(v3v.y); a2+=wz*u2f(v3v.z); a3+=wq*u2f(v3v.w);
        if (j+7<deg) v3v=ldrow(j+7); }
    }
  } else {
    // fallback: old multi-pass path (deg > 64; vanishingly rare)
    float mx0=-1e30f, mx1=-1e30f, mx2=-1e30f, mx3=-1e30f;
    for (int i=beg+lane; i<end; i+=64){
      int m = ep[i]; int n = nidx[m];
      float4 g = *(const float4*)(G + (size_t)n*12 + t*4);
      mx0=fmaxf(mx0,g.x); mx1=fmaxf(mx1,g.y); mx2=fmaxf(mx2,g.z); mx3=fmaxf(mx3,g.w);
    }
    #pragma unroll
    for (int d=1; d<64; d<<=1){
      mx0=fmaxf(mx0,__shfl_xor(mx0,d,64)); mx1=fmaxf(mx1,__shfl_xor(mx1,d,64));
      mx2=fmaxf(mx2,__shfl_xor(mx2,d,64)); mx3=fmaxf(mx3,__shfl_xor(mx3,d,64));
    }
    float sm0=0,sm1=0,sm2=0,sm3=0;
    for (int i=beg+lane; i<end; i+=64){
      int m = ep[i]; int n = nidx[m];
      float4 g = *(const float4*)(G + (size_t)n*12 + t*4);
      sm0+=__expf(g.x-mx0); sm1+=__expf(g.y-mx1); sm2+=__expf(g.z-mx2); sm3+=__expf(g.w-mx3);
    }
    #pragma unroll
    for (int d=1; d<64; d<<=1){
      sm0+=__shfl_xor(sm0,d,64); sm1+=__shfl_xor(sm1,d,64);
      sm2+=__shfl_xor(sm2,d,64); sm3+=__shfl_xor(sm3,d,64);
    }
    float inv0=1.f/sm0, inv1=1.f/sm1, inv2=1.f/sm2, inv3=1.f/sm3;
    for (int i=beg+lane; i<end; i+=64){
      int m = ep[i]; int n = nidx[m];
      float4 g = *(const float4*)(G + (size_t)n*12 + t*4);
      float4 w;
      w.x=__expf(g.x-mx0)*inv0; w.y=__expf(g.y-mx1)*inv1;
      w.z=__expf(g.z-mx2)*inv2; w.w=__expf(g.w-mx3)*inv3;
      *(float4*)(attn + (size_t)m*4) = w;
    }
    for (int i=beg; i<end; ++i){
      int m = ep[i]; int n = nidx[m];
      float4 g = *(const float4*)(G + (size_t)n*12 + t*4);
      float w0=__expf(g.x-mx0)*inv0, w1=__expf(g.y-mx1)*inv1;
      float w2=__expf(g.z-mx2)*inv2, w3=__expf(g.w-mx3)*inv3;
      ushort4 v = *(const ushort4*)(V16 + (size_t)n*256 + lane*4);
      a0 += w0*u2f(v.x); a1 += w1*u2f(v.y); a2 += w2*u2f(v.z); a3 += w3*u2f(v.w);
    }
  }
  ushort4 ev; ev.x=f2u(a0); ev.y=f2u(a1); ev.z=f2u(a2); ev.w=f2u(a3);
  *(ushort4*)(EF16 + (size_t)e*256 + lane*4) = ev;
}

// ---------------- per-node gather + residual + LayerNorm (pipelined) ----------------
__global__ __launch_bounds__(256) void k_node(const int* __restrict__ noff, const int* __restrict__ np,
    const int* __restrict__ eidx, const float* __restrict__ attn, const unsigned short* __restrict__ EF16,
    const float* __restrict__ lng, const float* __restrict__ lnb,
    bf16* __restrict__ h16, void* __restrict__ outv, const int* __restrict__ flag, int last){
  int n = blockIdx.x*4 + (threadIdx.x>>6);
  int lane = threadIdx.x & 63;
  if (n >= N_) return;
  float f0=0,f1=0,f2=0,f3=0;
  int beg = noff[n], end = noff[n+1];
  int deg = end - beg;
  if (deg > 0 && deg <= 64){
    int i = beg + lane;
    int e = 0;
    float4 w; w.x=w.y=w.z=w.w=0.f;
    if (lane < deg){
      int m = np[i]; e = eidx[m];
      w = *(const float4*)(attn + (size_t)m*4);
    }
    auto ldrow = [&](int j)->ushort4{
      int ee = __shfl(e, j, 64);
      return *(const ushort4*)(EF16 + (size_t)ee*256 + (lane<<2));
    };
    ushort4 v0v,v1v,v2v,v3v;
    if (deg>0) v0v=ldrow(0);
    if (deg>1) v1v=ldrow(1);
    if (deg>2) v2v=ldrow(2);
    if (deg>3) v3v=ldrow(3);
    for (int j=0;j<deg;j+=4){
      { float wx=__shfl(w.x,j,64),wy=__shfl(w.y,j,64),wz=__shfl(w.z,j,64),wq=__shfl(w.w,j,64);
        f0+=wx*u2f(v0v.x); f1+=wy*u2f(v0v.y); f2+=wz*u2f(v0v.z); f3+=wq*u2f(v0v.w);
        if (j+4<deg) v0v=ldrow(j+4); }
      if (j+1<deg){
        float wx=__shfl(w.x,j+1,64),wy=__shfl(w.y,j+1,64),wz=__shfl(w.z,j+1,64),wq=__shfl(w.w,j+1,64);
        f0+=wx*u2f(v1v.x); f1+=wy*u2f(v1v.y); f2+=wz*u2f(v1v.z); f3+=wq*u2f(v1v.w);
        if (j+5<deg) v1v=ldrow(j+5); }
      if (j+2<deg){
        float wx=__shfl(w.x,j+2,64),wy=__shfl(w.y,j+2,64),wz=__shfl(w.z,j+2,64),wq=__shfl(w.w,j+2,64);
        f0+=wx*u2f(v2v.x); f1+=wy*u2f(v2v.y); f2+=wz*u2f(v2v.z); f3+=wq*u2f(v2v.w);
        if (j+6<deg) v2v=ldrow(j+6); }
      if (j+3<deg){
        float wx=__shfl(w.x,j+3,64),wy=__shfl(w.y,j+3,64),wz=__shfl(w.z,j+3,64),wq=__shfl(w.w,j+3,64);
        f0+=wx*u2f(v3v.x); f1+=wy*u2f(v3v.y); f2+=wz*u2f(v3v.z); f3+=wq*u2f(v3v.w);
        if (j+7<deg) v3v=ldrow(j+7); }
    }
  } else if (deg > 64){
    for (int i=beg; i<end; ++i){
      int m = np[i]; int e = eidx[m];
      float4 w = *(const float4*)(attn + (size_t)m*4);
      ushort4 v = *(const ushort4*)(EF16 + (size_t)e*256 + lane*4);
      f0 += w.x*u2f(v.x); f1 += w.y*u2f(v.y); f2 += w.z*u2f(v.z); f3 += w.w*u2f(v.w);
    }
  }
  const bf16* hp = h16 + (size_t)n*256;
  float h0 = b2f(hp[lane])+f0, h1 = b2f(hp[64+lane])+f1, h2 = b2f(hp[128+lane])+f2, h3 = b2f(hp[192+lane])+f3;
  float s = h0+h1+h2+h3;
  #pragma unroll
  for (int d=1; d<64; d<<=1) s += __shfl_xor(s,d,64);
  float mean = s * (1.f/256.f);
  float d0=h0-mean, d1=h1-mean, d2=h2-mean, d3=h3-mean;
  float vv = d0*d0+d1*d1+d2*d2+d3*d3;
  #pragma unroll
  for (int d=1; d<64; d<<=1) vv += __shfl_xor(vv,d,64);
  float rstd = rsqrtf(vv*(1.f/256.f) + 1e-5f);
  float o0 = d0*rstd*lng[lane]     + lnb[lane];
  float o1 = d1*rstd*lng[64+lane]  + lnb[64+lane];
  float o2 = d2*rstd*lng[128+lane] + lnb[128+lane];
  float o3 = d3*rstd*lng[192+lane] + lnb[192+lane];
  if (last){
    if (*flag){
      bf16* op = (bf16*)outv + (size_t)n*256;
      op[lane]=__float2bfloat16(o0); op[64+lane]=__float2bfloat16(o1);
      op[128+lane]=__float2bfloat16(o2); op[192+lane]=__float2bfloat16(o3);
    } else {
      float* op = (float*)outv + (size_t)n*256;
      op[lane]=o0; op[64+lane]=o1; op[128+lane]=o2; op[192+lane]=o3;
    }
  } else {
    bf16* o16 = h16 + (size_t)n*256;
    o16[lane]=__float2bfloat16(o0); o16[64+lane]=__float2bfloat16(o1);
    o16[128+lane]=__float2bfloat16(o2); o16[192+lane]=__float2bfloat16(o3);
  }
}

extern "C" void kernel_launch(void* const* d_in, const int* in_sizes, int n_in,
                              void* d_out, int out_size, void* d_ws, size_t ws_size,
                              hipStream_t stream){
  const void* x    = d_in[0];
  const int* ntype = (const int*)d_in[1];
  const int* etype = (const int*)d_in[2];
  const int* nidx  = (const int*)d_in[3];
  const int* eidx  = (const int*)d_in[4];
  (void)in_sizes; (void)n_in; (void)out_size; (void)ws_size;

  char* ws = (char*)d_ws;
  size_t o = 0;
  auto alloc = [&](size_t b)->char*{ char* r = ws + o; o = (o + b + 255) & ~(size_t)255; return r; };
  int*   flag = (int*)  alloc(256);
  char*  R2   =         alloc((size_t)28000000);          // Hb+S during gemm/gate; attn+EF16 during edge/node
  float* G    = (float*)alloc((size_t)N_*12*4);
  float* tq_f  = (float*)alloc(1536*4);
  float* w1_f  = (float*)alloc(81920*4);
  float* b1_f  = (float*)alloc(256*4);
  float* w2_f  = (float*)alloc(256*4);
  float* b2_f  = (float*)alloc(8*4);
  float* wq_f  = (float*)alloc(131072*4);
  float* wv_f  = (float*)alloc(131072*4);
  float* ec_f  = (float*)alloc(1536*4);
  float* lng_f = (float*)alloc(512*4);
  float* lnb_f = (float*)alloc(512*4);
  float* wqe   = (float*)alloc(6144*4);
  float* pre   = (float*)alloc(768*4);
  int* cnt_e  = (int*)alloc((size_t)E_*4);
  int* cnt_n  = (int*)alloc((size_t)N_*4);
  int* eoff   = (int*)alloc((size_t)(E_+1)*4);
  int* noff   = (int*)alloc((size_t)(N_+1)*4);
  int* cur_e  = (int*)alloc((size_t)E_*4);
  int* cur_n  = (int*)alloc((size_t)N_*4);
  int* ep     = (int*)alloc((size_t)M_*4);
  int* np     = (int*)alloc((size_t)M_*4);
  int* bsum   = (int*)alloc(256*4);
  bf16* h16   = (bf16*)alloc((size_t)NPAD_*256*2);        // 25.6 MB bf16 hidden state (A for MFMA)
  bf16* Bp    = (bf16*)alloc((size_t)2*448*256*2);
  bf16* V16   = (bf16*)alloc((size_t)N_*256*2);           // 25.6 MB interleaved [n][d][h]

  float* Hb   = (float*)R2;
  float* S    = (float*)(R2 + 25600000);
  float* attn = (float*)R2;
  unsigned short* EF16 = (unsigned short*)(R2 + (size_t)M_*4*4);

  const int NB_E = (E_+255)/256, NB_N = (N_+255)/256;

  k_sniff<<<1, 256, 0, stream>>>((const unsigned short*)x, flag);
  k_cvt16<<<(N_*256+255)/256, 256, 0, stream>>>(x, h16, N_*256, flag);
  k_cvt<<<(1536+255)/256,   256, 0, stream>>>(d_in[5],  tq_f,  1536,   flag);
  k_cvt<<<(81920+255)/256,  256, 0, stream>>>(d_in[6],  w1_f,  81920,  flag);
  k_cvt<<<1,                256, 0, stream>>>(d_in[7],  b1_f,  256,    flag);
  k_cvt<<<1,                256, 0, stream>>>(d_in[8],  w2_f,  256,    flag);
  k_cvt<<<1,                256, 0, stream>>>(d_in[9],  b2_f,  8,      flag);
  k_cvt<<<(131072+255)/256, 256, 0, stream>>>(d_in[10], wq_f,  131072, flag);
  k_cvt<<<(131072+255)/256, 256, 0, stream>>>(d_in[11], wv_f,  131072, flag);
  k_cvt<<<(1536+255)/256,   256, 0, stream>>>(d_in[12], ec_f,  1536,   flag);
  k_cvt<<<2,                256, 0, stream>>>(d_in[13], lng_f, 512,    flag);
  k_cvt<<<2,                256, 0, stream>>>(d_in[14], lnb_f, 512,    flag);

  k_zero<<<NB_E, 256, 0, stream>>>(cnt_e, E_);
  k_zero<<<NB_N, 256, 0, stream>>>(cnt_n, N_);
  k_hist<<<M_/256, 256, 0, stream>>>(eidx, nidx, cnt_e, cnt_n);
  k_scan1<<<NB_E, 256, 0, stream>>>(cnt_e, eoff, bsum, E_);
  k_scan2<<<1, 256, 0, stream>>>(bsum, eoff, NB_E, E_);
  k_scan3<<<NB_E, 256, 0, stream>>>(bsum, eoff, cur_e, E_);
  k_scan1<<<NB_N, 256, 0, stream>>>(cnt_n, noff, bsum, N_);
  k_scan2<<<1, 256, 0, stream>>>(bsum, noff, NB_N, N_);
  k_scan3<<<NB_N, 256, 0, stream>>>(bsum, noff, cur_n, N_);
  k_fill<<<M_/256, 256, 0, stream>>>(eidx, nidx, cur_e, cur_n, ep, np);
  k_pre<<<3, 256, 0, stream>>>(tq_f, w1_f, b1_f, pre);
  k_wqe<<<24, 256, 0, stream>>>(wq_f, ec_f, wqe);
  k_bpack<<<(2*448*256+255)/256, 256, 0, stream>>>(wv_f, w1_f, wqe, Bp);

  for (int l=0; l<2; ++l){
    k_mgemm<<<dim3(7,391), 256, 0, stream>>>(h16, Bp + (size_t)l*448*256, V16, Hb, S);
    k_gate<<<12500, 256, 0, stream>>>(Hb, S, pre + l*384, w2_f + l*128, b2_f + l*4, ntype, G);
    k_edge<<<5000, 256, 0, stream>>>(eoff, ep, nidx, etype, G, (const unsigned short*)V16, attn, EF16);
    k_node<<<12500, 256, 0, stream>>>(noff, np, eidx, attn, EF16, lng_f + l*256, lnb_f + l*256,
                                      h16, d_out, flag, l==1);
  }
}

// Round 7
// 549.243 us; speedup vs baseline: 2.7189x; 1.0633x over previous
//
#include <hip/hip_runtime.h>
#include <hip/hip_bf16.h>

typedef __hip_bfloat16 bf16;
using short8  = __attribute__((ext_vector_type(8))) short;
using float4v = __attribute__((ext_vector_type(4))) float;

static constexpr int N_ = 50000;   // nodes
static constexpr int E_ = 20000;   // hyperedges
static constexpr int M_ = 320000;  // incidence pairs
static constexpr int NPAD_ = 50048;  // 391*128 rows for MFMA grid
static constexpr int NB_E = (E_+255)/256;   // 79
static constexpr int NB_N = (N_+255)/256;   // 196

__device__ __forceinline__ float b2f(bf16 v){ return __bfloat162float(v); }
__device__ __forceinline__ float sigm(float x){ return 1.f/(1.f+__expf(-x)); }
__device__ __forceinline__ float u2f(unsigned short u){ return __uint_as_float(((unsigned)u)<<16); }
__device__ __forceinline__ unsigned short f2u(float f){ bf16 t=__float2bfloat16(f); return *(unsigned short*)&t; }

// ---------------- dtype sniff ----------------
__global__ __launch_bounds__(256) void k_sniff(const unsigned short* __restrict__ xb, int* flag){
  int tid = threadIdx.x;
  int sane = 0;
  for (int i = tid; i < 4096; i += 256){
    unsigned short u = xb[2*i];
    int ex = (u >> 7) & 0xFF;
    if ((u & 0x7FFF) == 0 || (ex >= 117 && ex <= 137)) sane++;
  }
  #pragma unroll
  for (int d=1; d<64; d<<=1) sane += __shfl_xor(sane, d, 64);
  __shared__ int wsh[4];
  if ((tid&63)==0) wsh[tid>>6] = sane;
  __syncthreads();
  if (tid==0){
    int tot = wsh[0]+wsh[1]+wsh[2]+wsh[3];
    *flag = (tot > 2048) ? 1 : 0;    // 1 = bf16 storage
  }
}

// ---------------- converts ----------------
__global__ __launch_bounds__(256) void k_cvt16(const void* __restrict__ src, bf16* __restrict__ dst,
                                               int n, const int* __restrict__ flag){
  int i = blockIdx.x*256 + threadIdx.x;
  if (i >= n) return;
  if (*flag) dst[i] = ((const bf16*)src)[i];
  else       dst[i] = __float2bfloat16(((const float*)src)[i]);
}

// all 10 small weight tensors -> fp32, one launch
__global__ __launch_bounds__(256) void k_cvtall(
    const void* s0, const void* s1, const void* s2, const void* s3, const void* s4,
    const void* s5, const void* s6, const void* s7, const void* s8, const void* s9,
    float* d0, float* d1, float* d2, float* d3, float* d4,
    float* d5, float* d6, float* d7, float* d8, float* d9,
    const int* __restrict__ flag){
  int i = blockIdx.x*256 + threadIdx.x;
  const void* src; float* dst; int off;
  if      (i < 1536)            { src=s0; dst=d0; off=i; }
  else if (i < 1536+81920)      { src=s1; dst=d1; off=i-1536; }
  else if (i < 83712+256)       { src=s2; dst=d2; off=i-83712; }
  else if (i < 83968+256)       { src=s3; dst=d3; off=i-83968; }
  else if (i < 84224+8)         { src=s4; dst=d4; off=i-84224; }
  else if (i < 84232+131072)    { src=s5; dst=d5; off=i-84232; }
  else if (i < 215304+131072)   { src=s6; dst=d6; off=i-215304; }
  else if (i < 346376+1536)     { src=s7; dst=d7; off=i-346376; }
  else if (i < 347912+512)      { src=s8; dst=d8; off=i-347912; }
  else if (i < 348424+512)      { src=s9; dst=d9; off=i-348424; }
  else return;
  if (*flag) dst[off] = b2f(((const bf16*)src)[off]);
  else       dst[off] = ((const float*)src)[off];
}

__global__ __launch_bounds__(256) void k_zero2(int* pe, int* pn){
  int i = blockIdx.x*256 + threadIdx.x;
  if (i < E_) pe[i] = 0;
  else if (i < E_+N_) pn[i-E_] = 0;
}

// ---------------- CSR build ----------------
__global__ __launch_bounds__(256) void k_hist(const int* __restrict__ eidx, const int* __restrict__ nidx,
                                              int* cnt_e, int* cnt_n){
  int m = blockIdx.x*256 + threadIdx.x;
  if (m < M_){ atomicAdd(&cnt_e[eidx[m]],1); atomicAdd(&cnt_n[nidx[m]],1); }
}

__device__ __forceinline__ void scan1_body(const int* cnt, int* off, int* bsum, int n, int blk){
  int tid = threadIdx.x, lane = tid&63, wid = tid>>6;
  int i = blk*256 + tid;
  int v = (i<n)? cnt[i] : 0;
  int s = v;
  #pragma unroll
  for (int d=1; d<64; d<<=1){ int t = __shfl_up(s, d, 64); if (lane>=d) s += t; }
  __shared__ int ws[4]; __shared__ int wo[4];
  if (lane==63) ws[wid] = s;
  __syncthreads();
  if (tid==0){ int a=0; for (int k=0;k<4;k++){ int t=ws[k]; wo[k]=a; a+=t; } bsum[blk]=a; }
  __syncthreads();
  if (i<n) off[i] = wo[wid] + s - v;
}

__global__ __launch_bounds__(256) void k_scan1m(const int* __restrict__ cnt_e, int* __restrict__ eoff, int* bsum_e,
                                                const int* __restrict__ cnt_n, int* __restrict__ noff, int* bsum_n){
  int b = blockIdx.x;
  if (b < NB_E) scan1_body(cnt_e, eoff, bsum_e, E_, b);
  else          scan1_body(cnt_n, noff, bsum_n, N_, b-NB_E);
}

__device__ __forceinline__ void scan2_body(int* bsum, int* off, int nb, int n){
  int tid = threadIdx.x, lane = tid&63, wid = tid>>6;
  int v = (tid<nb)? bsum[tid] : 0;
  int s = v;
  #pragma unroll
  for (int d=1; d<64; d<<=1){ int t = __shfl_up(s, d, 64); if (lane>=d) s += t; }
  __shared__ int ws[4]; __shared__ int wo[4];
  if (lane==63) ws[wid] = s;
  __syncthreads();
  if (tid==0){ int a=0; for (int k=0;k<4;k++){ int t=ws[k]; wo[k]=a; a+=t; } off[n]=a; }
  __syncthreads();
  if (tid<nb) bsum[tid] = wo[wid] + s - v;
}

__global__ __launch_bounds__(256) void k_scan2m(int* bsum_e, int* __restrict__ eoff,
                                                int* bsum_n, int* __restrict__ noff){
  if (blockIdx.x == 0) scan2_body(bsum_e, eoff, NB_E, E_);
  else                 scan2_body(bsum_n, noff, NB_N, N_);
}

__global__ __launch_bounds__(256) void k_scan3m(const int* __restrict__ bsum_e, int* __restrict__ eoff, int* cur_e,
                                                const int* __restrict__ bsum_n, int* __restrict__ noff, int* cur_n){
  int b = blockIdx.x;
  if (b < NB_E){
    int i = b*256 + threadIdx.x;
    if (i<E_){ int e = eoff[i] + bsum_e[b]; eoff[i]=e; cur_e[i]=e; }
  } else {
    int i = (b-NB_E)*256 + threadIdx.x;
    if (i<N_){ int e = noff[i] + bsum_n[b-NB_E]; noff[i]=e; cur_n[i]=e; }
  }
}

__global__ __launch_bounds__(256) void k_fill(const int* __restrict__ eidx, const int* __restrict__ nidx,
                                              int* cur_e, int* cur_n, int* ep, int* np){
  int m = blockIdx.x*256 + threadIdx.x;
  if (m < M_){
    int p = atomicAdd(&cur_e[eidx[m]],1); ep[p]=m;
    int q = atomicAdd(&cur_n[nidx[m]],1); np[q]=m;
  }
}

// ---------------- pre / wqe / bpack ----------------
__global__ __launch_bounds__(256) void k_pre(const float* __restrict__ tq, const float* __restrict__ w1,
                                             const float* __restrict__ b1, float* __restrict__ pre){
  int idx = blockIdx.x*256 + threadIdx.x;
  if (idx >= 768) return;
  int l = idx / 384, r = idx % 384;
  int t = r / 128, r2 = r % 128;
  int h = r2 >> 5, k = r2 & 31;
  const float* tp = tq + ((l*4+h)*3 + t)*64;
  const float* wp = w1 + (size_t)((l*4+h)*32 + k)*320 + 256;
  float s = b1[(l*4+h)*32 + k];
  for (int d=0; d<64; ++d) s += tp[d]*wp[d];
  pre[(l*3+t)*128 + r2] = s;
}

__global__ __launch_bounds__(256) void k_wqe(const float* __restrict__ wq_f, const float* __restrict__ ec_f,
                                             float* __restrict__ wqe){
  int b = blockIdx.x;
  int l = b/12, ht = b%12, h = ht/3, t = ht%3;
  int d = threadIdx.x;
  const float* ecp = ec_f + ((l*4+h)*3 + t)*64;
  const float* wqp = wq_f + (size_t)((l*4+h)*64)*256;
  float s = 0.f;
  for (int o=0;o<64;++o) s += ecp[o]*wqp[o*256 + d];
  wqe[(size_t)(l*12+ht)*256 + d] = s;
}

// pack B panel with V cols PERMUTED to the V16 interleave order:
// packed c<256: d=c>>2, h=c&3 -> original V col h*64+d (wv row h*64+d)
__global__ __launch_bounds__(256) void k_bpack(const float* __restrict__ wv_f, const float* __restrict__ w1_f,
                                               const float* __restrict__ wqe, bf16* __restrict__ Bp){
  int idx = blockIdx.x*256 + threadIdx.x;
  if (idx >= 2*448*256) return;
  int l = idx / (448*256), r = idx % (448*256);
  int c = r >> 8, k = r & 255;
  float v = 0.f;
  if (c < 256){
    int dd = c >> 2, h = c & 3;
    v = wv_f[(size_t)l*65536 + (size_t)(h*64+dd)*256 + k];
  }
  else if (c < 384) v = w1_f[(size_t)l*40960 + (size_t)(c-256)*320 + k];
  else if (c < 396) v = wqe[(size_t)(l*12 + c-384)*256 + k];
  Bp[idx] = __float2bfloat16(v);
}

// ---------------- MFMA GEMM, XCD-swizzled 1-D grid (2744 blocks) ----------------
// decode: g -> r8=g&7, k=g>>3, x=k/49, yhi=k%49, y=yhi*8+r8  => all 7 x-blocks of a row share g%8 (same XCD)
// V cols are pre-permuted so V16 writes are CONTIGUOUS 2-byte runs (full-line coverage).
__global__ __launch_bounds__(256) void k_mgemm(const bf16* __restrict__ A16, const bf16* __restrict__ Bp,
    bf16* __restrict__ V16, bf16* __restrict__ Hb16, float* __restrict__ S){
  int g = blockIdx.x;
  int r8 = g & 7, kk = g >> 3;
  int x = kk / 49, yhi = kk % 49;
  int y = yhi*8 + r8;
  if (y >= 391 || x >= 7) return;
  int wid = threadIdx.x >> 6, lane = threadIdx.x & 63;
  int q = lane >> 4, li = lane & 15;
  int row0 = y*128 + wid*32;
  int col0 = x*64;
  float4v acc[2][4];
  #pragma unroll
  for (int i=0;i<2;i++)
    #pragma unroll
    for (int j=0;j<4;j++) acc[i][j] = (float4v)(0.f);
  const bf16* a0p = A16 + (size_t)(row0 + li)*256;
  const bf16* a1p = A16 + (size_t)(row0 + 16 + li)*256;
  const bf16* bp  = Bp  + (size_t)(col0 + li)*256;
  #pragma unroll
  for (int kc=0; kc<256; kc+=32){
    int ko = kc + q*8;
    short8 a0 = *(const short8*)(a0p + ko);
    short8 a1 = *(const short8*)(a1p + ko);
    short8 b0 = *(const short8*)(bp + ko);
    short8 b1 = *(const short8*)(bp + 16*256 + ko);
    short8 b2 = *(const short8*)(bp + 32*256 + ko);
    short8 b3 = *(const short8*)(bp + 48*256 + ko);
    acc[0][0] = __builtin_amdgcn_mfma_f32_16x16x32_bf16(a0,b0,acc[0][0],0,0,0);
    acc[0][1] = __builtin_amdgcn_mfma_f32_16x16x32_bf16(a0,b1,acc[0][1],0,0,0);
    acc[0][2] = __builtin_amdgcn_mfma_f32_16x16x32_bf16(a0,b2,acc[0][2],0,0,0);
    acc[0][3] = __builtin_amdgcn_mfma_f32_16x16x32_bf16(a0,b3,acc[0][3],0,0,0);
    acc[1][0] = __builtin_amdgcn_mfma_f32_16x16x32_bf16(a1,b0,acc[1][0],0,0,0);
    acc[1][1] = __builtin_amdgcn_mfma_f32_16x16x32_bf16(a1,b1,acc[1][1],0,0,0);
    acc[1][2] = __builtin_amdgcn_mfma_f32_16x16x32_bf16(a1,b2,acc[1][2],0,0,0);
    acc[1][3] = __builtin_amdgcn_mfma_f32_16x16x32_bf16(a1,b3,acc[1][3],0,0,0);
  }
  #pragma unroll
  for (int i=0;i<2;i++){
    #pragma unroll
    for (int r=0;r<4;r++){
      int grow = row0 + i*16 + q*4 + r;
      if (grow >= N_) continue;
      #pragma unroll
      for (int j=0;j<4;j++){
        int gc = col0 + j*16 + li;
        float v = acc[i][j][r];
        if (gc < 256)      V16 [(size_t)grow*256 + gc]       = __float2bfloat16(v);  // contiguous (permuted)
        else if (gc < 384) Hb16[(size_t)grow*128 + gc - 256] = __float2bfloat16(v);
        else if (gc < 396) S   [(size_t)grow*12  + gc - 384] = v;
      }
    }
  }
}

// ---------------- per-node gate (Hb now bf16) ----------------
__global__ __launch_bounds__(256) void k_gate(const unsigned short* __restrict__ Hb16, const float* __restrict__ S,
    const float* __restrict__ pre_l, const float* __restrict__ w2_l, const float* __restrict__ b2_l,
    const int* __restrict__ ntype, float* __restrict__ G){
  int node = blockIdx.x*4 + (threadIdx.x>>6);
  int lane = threadIdx.x & 63;
  if (node >= N_) return;
  int typ = ntype[node];
  const float* pr = pre_l + typ*128;
  float v0 = tanhf(u2f(Hb16[(size_t)node*128 + lane])      + pr[lane]);
  float v1 = tanhf(u2f(Hb16[(size_t)node*128 + 64 + lane]) + pr[64+lane]);
  float p0 = v0 * w2_l[lane];
  float p1 = v1 * w2_l[64+lane];
  #pragma unroll
  for (int d=1; d<32; d<<=1){ p0 += __shfl_xor(p0,d,64); p1 += __shfl_xor(p1,d,64); }
  float at0 = sigm(__shfl(p0, 0,64) + b2_l[0]);
  float at1 = sigm(__shfl(p0,32,64) + b2_l[1]);
  float at2 = sigm(__shfl(p1, 0,64) + b2_l[2]);
  float at3 = sigm(__shfl(p1,32,64) + b2_l[3]);
  if (lane < 12){
    int h = lane / 3, t = lane % 3;
    float sv = S[(size_t)node*12 + lane];
    float lr = (sv > 0.f) ? sv : 0.2f*sv;
    float av = (h==0)? at0 : (h==1)? at1 : (h==2)? at2 : at3;
    G[(size_t)node*12 + t*4 + h] = lr * av;
  }
}

// ---------------- per-edge softmax + edge_feat (single-pass, pipelined gather) ----------------
__global__ __launch_bounds__(256) void k_edge(const int* __restrict__ eoff, const int* __restrict__ ep,
    const int* __restrict__ nidx, const int* __restrict__ etype,
    const float* __restrict__ G, const unsigned short* __restrict__ V16,
    float* __restrict__ attn, unsigned short* __restrict__ EF16){
  int e = blockIdx.x*4 + (threadIdx.x>>6);
  int lane = threadIdx.x & 63;
  if (e >= E_) return;
  int beg = eoff[e], end = eoff[e+1];
  int deg = end - beg;
  if (deg == 0) return;
  int t = etype[e];
  float a0=0,a1=0,a2=0,a3=0;

  if (deg <= 64){
    int i = beg + lane;
    int m = -1, n = 0;
    float4 g; g.x=g.y=g.z=g.w=-1e30f;
    if (lane < deg){
      m = ep[i]; n = nidx[m];
      g = *(const float4*)(G + (size_t)n*12 + t*4);
    }
    float mx0=g.x, mx1=g.y, mx2=g.z, mx3=g.w;
    #pragma unroll
    for (int d=1; d<64; d<<=1){
      mx0=fmaxf(mx0,__shfl_xor(mx0,d,64)); mx1=fmaxf(mx1,__shfl_xor(mx1,d,64));
      mx2=fmaxf(mx2,__shfl_xor(mx2,d,64)); mx3=fmaxf(mx3,__shfl_xor(mx3,d,64));
    }
    float ex0=0,ex1=0,ex2=0,ex3=0;
    if (lane < deg){
      ex0=__expf(g.x-mx0); ex1=__expf(g.y-mx1); ex2=__expf(g.z-mx2); ex3=__expf(g.w-mx3);
    }
    float s0=ex0,s1=ex1,s2=ex2,s3=ex3;
    #pragma unroll
    for (int d=1; d<64; d<<=1){
      s0+=__shfl_xor(s0,d,64); s1+=__shfl_xor(s1,d,64);
      s2+=__shfl_xor(s2,d,64); s3+=__shfl_xor(s3,d,64);
    }
    float4 w; w.x=ex0/s0; w.y=ex1/s1; w.z=ex2/s2; w.w=ex3/s3;
    if (lane < deg) *(float4*)(attn + (size_t)m*4) = w;
    auto ldrow = [&](int j)->ushort4{
      int nn = __shfl(n, j, 64);
      return *(const ushort4*)(V16 + (size_t)nn*256 + (lane<<2));
    };
    ushort4 v0v,v1v,v2v,v3v;
    if (deg>0) v0v=ldrow(0);
    if (deg>1) v1v=ldrow(1);
    if (deg>2) v2v=ldrow(2);
    if (deg>3) v3v=ldrow(3);
    for (int j=0;j<deg;j+=4){
      { float wx=__shfl(w.x,j,64),wy=__shfl(w.y,j,64),wz=__shfl(w.z,j,64),wq=__shfl(w.w,j,64);
        a0+=wx*u2f(v0v.x); a1+=wy*u2f(v0v.y); a2+=wz*u2f(v0v.z); a3+=wq*u2f(v0v.w);
        if (j+4<deg) v0v=ldrow(j+4); }
      if (j+1<deg){
        float wx=__shfl(w.x,j+1,64),wy=__shfl(w.y,j+1,64),wz=__shfl(w.z,j+1,64),wq=__shfl(w.w,j+1,64);
        a0+=wx*u2f(v1v.x); a1+=wy*u2f(v1v.y); a2+=wz*u2f(v1v.z); a3+=wq*u2f(v1v.w);
        if (j+5<deg) v1v=ldrow(j+5); }
      if (j+2<deg){
        float wx=__shfl(w.x,j+2,64),wy=__shfl(w.y,j+2,64),wz=__shfl(w.z,j+2,64),wq=__shfl(w.w,j+2,64);
        a0+=wx*u2f(v2v.x); a1+=wy*u2f(v2v.y); a2+=wz*u2f(v2v.z); a3+=wq*u2f(v2v.w);
        if (j+6<deg) v2v=ldrow(j+6); }
      if (j+3<deg){
        float wx=__shfl(w.x,j+3,64),wy=__shfl(w.y,j+3,64),wz=__shfl(w.z,j+3,64),wq=__shfl(w.w,j+3,64);
        a0+=wx*u2f(v3v.x); a1+=wy*u2f(v3v.y); a2+=wz*u2f(v3v.z); a3+=wq*u2f(v3v.w);
        if (j+7<deg) v3v=ldrow(j+7); }
    }
  } else {
    float mx0=-1e30f, mx1=-1e30f, mx2=-1e30f, mx3=-1e30f;
    for (int i=beg+lane; i<end; i+=64){
      int m = ep[i]; int n = nidx[m];
      float4 g = *(const float4*)(G + (size_t)n*12 + t*4);
      mx0=fmaxf(mx0,g.x); mx1=fmaxf(mx1,g.y); mx2=fmaxf(mx2,g.z); mx3=fmaxf(mx3,g.w);
    }
    #pragma unroll
    for (int d=1; d<64; d<<=1){
      mx0=fmaxf(mx0,__shfl_xor(mx0,d,64)); mx1=fmaxf(mx1,__shfl_xor(mx1,d,64));
      mx2=fmaxf(mx2,__shfl_xor(mx2,d,64)); mx3=fmaxf(mx3,__shfl_xor(mx3,d,64));
    }
    float sm0=0,sm1=0,sm2=0,sm3=0;
    for (int i=beg+lane; i<end; i+=64){
      int m = ep[i]; int n = nidx[m];
      float4 g = *(const float4*)(G + (size_t)n*12 + t*4);
      sm0+=__expf(g.x-mx0); sm1+=__expf(g.y-mx1); sm2+=__expf(g.z-mx2); sm3+=__expf(g.w-mx3);
    }
    #pragma unroll
    for (int d=1; d<64; d<<=1){
      sm0+=__shfl_xor(sm0,d,64); sm1+=__shfl_xor(sm1,d,64);
      sm2+=__shfl_xor(sm2,d,64); sm3+=__shfl_xor(sm3,d,64);
    }
    float inv0=1.f/sm0, inv1=1.f/sm1, inv2=1.f/sm2, inv3=1.f/sm3;
    for (int i=beg+lane; i<end; i+=64){
      int m = ep[i]; int n = nidx[m];
      float4 g = *(const float4*)(G + (size_t)n*12 + t*4);
      float4 w;
      w.x=__expf(g.x-mx0)*inv0; w.y=__expf(g.y-mx1)*inv1;
      w.z=__expf(g.z-mx2)*inv2; w.w=__expf(g.w-mx3)*inv3;
      *(float4*)(attn + (size_t)m*4) = w;
    }
    for (int i=beg; i<end; ++i){
      int m = ep[i]; int n = nidx[m];
      float4 g = *(const float4*)(G + (size_t)n*12 + t*4);
      float w0=__expf(g.x-mx0)*inv0, w1=__expf(g.y-mx1)*inv1;
      float w2=__expf(g.z-mx2)*inv2, w3=__expf(g.w-mx3)*inv3;
      ushort4 v = *(const ushort4*)(V16 + (size_t)n*256 + lane*4);
      a0 += w0*u2f(v.x); a1 += w1*u2f(v.y); a2 += w2*u2f(v.z); a3 += w3*u2f(v.w);
    }
  }
  ushort4 ev; ev.x=f2u(a0); ev.y=f2u(a1); ev.z=f2u(a2); ev.w=f2u(a3);
  *(ushort4*)(EF16 + (size_t)e*256 + lane*4) = ev;
}

// ---------------- per-node gather + residual + LayerNorm (pipelined) ----------------
__global__ __launch_bounds__(256) void k_node(const int* __restrict__ noff, const int* __restrict__ np,
    const int* __restrict__ eidx, const float* __restrict__ attn, const unsigned short* __restrict__ EF16,
    const float* __restrict__ lng, const float* __restrict__ lnb,
    bf16* __restrict__ h16, void* __restrict__ outv, const int* __restrict__ flag, int last){
  int n = blockIdx.x*4 + (threadIdx.x>>6);
  int lane = threadIdx.x & 63;
  if (n >= N_) return;
  float f0=0,f1=0,f2=0,f3=0;
  int beg = noff[n], end = noff[n+1];
  int deg = end - beg;
  if (deg > 0 && deg <= 64){
    int i = beg + lane;
    int e = 0;
    float4 w; w.x=w.y=w.z=w.w=0.f;
    if (lane < deg){
      int m = np[i]; e = eidx[m];
      w = *(const float4*)(attn + (size_t)m*4);
    }
    auto ldrow = [&](int j)->ushort4{
      int ee = __shfl(e, j, 64);
      return *(const ushort4*)(EF16 + (size_t)ee*256 + (lane<<2));
    };
    ushort4 v0v,v1v,v2v,v3v;
    if (deg>0) v0v=ldrow(0);
    if (deg>1) v1v=ldrow(1);
    if (deg>2) v2v=ldrow(2);
    if (deg>3) v3v=ldrow(3);
    for (int j=0;j<deg;j+=4){
      { float wx=__shfl(w.x,j,64),wy=__shfl(w.y,j,64),wz=__shfl(w.z,j,64),wq=__shfl(w.w,j,64);
        f0+=wx*u2f(v0v.x); f1+=wy*u2f(v0v.y); f2+=wz*u2f(v0v.z); f3+=wq*u2f(v0v.w);
        if (j+4<deg) v0v=ldrow(j+4); }
      if (j+1<deg){
        float wx=__shfl(w.x,j+1,64),wy=__shfl(w.y,j+1,64),wz=__shfl(w.z,j+1,64),wq=__shfl(w.w,j+1,64);
        f0+=wx*u2f(v1v.x); f1+=wy*u2f(v1v.y); f2+=wz*u2f(v1v.z); f3+=wq*u2f(v1v.w);
        if (j+5<deg) v1v=ldrow(j+5); }
      if (j+2<deg){
        float wx=__shfl(w.x,j+2,64),wy=__shfl(w.y,j+2,64),wz=__shfl(w.z,j+2,64),wq=__shfl(w.w,j+2,64);
        f0+=wx*u2f(v2v.x); f1+=wy*u2f(v2v.y); f2+=wz*u2f(v2v.z); f3+=wq*u2f(v2v.w);
        if (j+6<deg) v2v=ldrow(j+6); }
      if (j+3<deg){
        float wx=__shfl(w.x,j+3,64),wy=__shfl(w.y,j+3,64),wz=__shfl(w.z,j+3,64),wq=__shfl(w.w,j+3,64);
        f0+=wx*u2f(v3v.x); f1+=wy*u2f(v3v.y); f2+=wz*u2f(v3v.z); f3+=wq*u2f(v3v.w);
        if (j+7<deg) v3v=ldrow(j+7); }
    }
  } else if (deg > 64){
    for (int i=beg; i<end; ++i){
      int m = np[i]; int e = eidx[m];
      float4 w = *(const float4*)(attn + (size_t)m*4);
      ushort4 v = *(const ushort4*)(EF16 + (size_t)e*256 + lane*4);
      f0 += w.x*u2f(v.x); f1 += w.y*u2f(v.y); f2 += w.z*u2f(v.z); f3 += w.w*u2f(v.w);
    }
  }
  const bf16* hp = h16 + (size_t)n*256;
  float h0 = b2f(hp[lane])+f0, h1 = b2f(hp[64+lane])+f1, h2 = b2f(hp[128+lane])+f2, h3 = b2f(hp[192+lane])+f3;
  float s = h0+h1+h2+h3;
  #pragma unroll
  for (int d=1; d<64; d<<=1) s += __shfl_xor(s,d,64);
  float mean = s * (1.f/256.f);
  float d0=h0-mean, d1=h1-mean, d2=h2-mean, d3=h3-mean;
  float vv = d0*d0+d1*d1+d2*d2+d3*d3;
  #pragma unroll
  for (int d=1; d<64; d<<=1) vv += __shfl_xor(vv,d,64);
  float rstd = rsqrtf(vv*(1.f/256.f) + 1e-5f);
  float o0 = d0*rstd*lng[lane]     + lnb[lane];
  float o1 = d1*rstd*lng[64+lane]  + lnb[64+lane];
  float o2 = d2*rstd*lng[128+lane] + lnb[128+lane];
  float o3 = d3*rstd*lng[192+lane] + lnb[192+lane];
  if (last){
    if (*flag){
      bf16* op = (bf16*)outv + (size_t)n*256;
      op[lane]=__float2bfloat16(o0); op[64+lane]=__float2bfloat16(o1);
      op[128+lane]=__float2bfloat16(o2); op[192+lane]=__float2bfloat16(o3);
    } else {
      float* op = (float*)outv + (size_t)n*256;
      op[lane]=o0; op[64+lane]=o1; op[128+lane]=o2; op[192+lane]=o3;
    }
  } else {
    bf16* o16 = h16 + (size_t)n*256;
    o16[lane]=__float2bfloat16(o0); o16[64+lane]=__float2bfloat16(o1);
    o16[128+lane]=__float2bfloat16(o2); o16[192+lane]=__float2bfloat16(o3);
  }
}

extern "C" void kernel_launch(void* const* d_in, const int* in_sizes, int n_in,
                              void* d_out, int out_size, void* d_ws, size_t ws_size,
                              hipStream_t stream){
  const void* x    = d_in[0];
  const int* ntype = (const int*)d_in[1];
  const int* etype = (const int*)d_in[2];
  const int* nidx  = (const int*)d_in[3];
  const int* eidx  = (const int*)d_in[4];
  (void)in_sizes; (void)n_in; (void)out_size; (void)ws_size;

  char* ws = (char*)d_ws;
  size_t o = 0;
  auto alloc = [&](size_t b)->char*{ char* r = ws + o; o = (o + b + 255) & ~(size_t)255; return r; };
  int*   flag = (int*)  alloc(256);
  char*  R2   =         alloc((size_t)20000000);          // Hb16+S (gemm->gate) / attn+EF16 (edge->node)
  float* G    = (float*)alloc((size_t)N_*12*4);
  float* tq_f  = (float*)alloc(1536*4);
  float* w1_f  = (float*)alloc(81920*4);
  float* b1_f  = (float*)alloc(256*4);
  float* w2_f  = (float*)alloc(256*4);
  float* b2_f  = (float*)alloc(8*4);
  float* wq_f  = (float*)alloc(131072*4);
  float* wv_f  = (float*)alloc(131072*4);
  float* ec_f  = (float*)alloc(1536*4);
  float* lng_f = (float*)alloc(512*4);
  float* lnb_f = (float*)alloc(512*4);
  float* wqe   = (float*)alloc(6144*4);
  float* pre   = (float*)alloc(768*4);
  int* cnt_e  = (int*)alloc((size_t)E_*4);
  int* cnt_n  = (int*)alloc((size_t)N_*4);
  int* eoff   = (int*)alloc((size_t)(E_+1)*4);
  int* noff   = (int*)alloc((size_t)(N_+1)*4);
  int* cur_e  = (int*)alloc((size_t)E_*4);
  int* cur_n  = (int*)alloc((size_t)N_*4);
  int* ep     = (int*)alloc((size_t)M_*4);
  int* np     = (int*)alloc((size_t)M_*4);
  int* bsum_e = (int*)alloc(256*4);
  int* bsum_n = (int*)alloc(256*4);
  bf16* h16   = (bf16*)alloc((size_t)NPAD_*256*2);        // 25.6 MB bf16 hidden state (A for MFMA)
  bf16* Bp    = (bf16*)alloc((size_t)2*448*256*2);
  bf16* V16   = (bf16*)alloc((size_t)N_*256*2);           // 25.6 MB interleaved [n][d][h]

  bf16*  Hb16 = (bf16*)R2;                                 // 12.8 MB
  float* S    = (float*)(R2 + 16777216);                   // 2.4 MB
  float* attn = (float*)R2;                                // 5.12 MB
  unsigned short* EF16 = (unsigned short*)(R2 + 5242880);  // 10.24 MB (ends 15.48M < S)

  k_sniff<<<1, 256, 0, stream>>>((const unsigned short*)x, flag);
  k_cvt16<<<(N_*256+255)/256, 256, 0, stream>>>(x, h16, N_*256, flag);
  k_cvtall<<<(348936+255)/256, 256, 0, stream>>>(
      d_in[5], d_in[6], d_in[7], d_in[8], d_in[9],
      d_in[10], d_in[11], d_in[12], d_in[13], d_in[14],
      tq_f, w1_f, b1_f, w2_f, b2_f, wq_f, wv_f, ec_f, lng_f, lnb_f, flag);

  k_zero2<<<(E_+N_+255)/256, 256, 0, stream>>>(cnt_e, cnt_n);
  k_hist<<<M_/256, 256, 0, stream>>>(eidx, nidx, cnt_e, cnt_n);
  k_scan1m<<<NB_E+NB_N, 256, 0, stream>>>(cnt_e, eoff, bsum_e, cnt_n, noff, bsum_n);
  k_scan2m<<<2, 256, 0, stream>>>(bsum_e, eoff, bsum_n, noff);
  k_scan3m<<<NB_E+NB_N, 256, 0, stream>>>(bsum_e, eoff, cur_e, bsum_n, noff, cur_n);
  k_fill<<<M_/256, 256, 0, stream>>>(eidx, nidx, cur_e, cur_n, ep, np);
  k_pre<<<3, 256, 0, stream>>>(tq_f, w1_f, b1_f, pre);
  k_wqe<<<24, 256, 0, stream>>>(wq_f, ec_f, wqe);
  k_bpack<<<(2*448*256+255)/256, 256, 0, stream>>>(wv_f, w1_f, wqe, Bp);

  for (int l=0; l<2; ++l){
    k_mgemm<<<2744, 256, 0, stream>>>(h16, Bp + (size_t)l*448*256, V16, Hb16, S);
    k_gate<<<12500, 256, 0, stream>>>((const unsigned short*)Hb16, S, pre + l*384,
                                      w2_f + l*128, b2_f + l*4, ntype, G);
    k_edge<<<5000, 256, 0, stream>>>(eoff, ep, nidx, etype, G, (const unsigned short*)V16, attn, EF16);
    k_node<<<12500, 256, 0, stream>>>(noff, np, eidx, attn, EF16, lng_f + l*256, lnb_f + l*256,
                                      h16, d_out, flag, l==1);
  }
}

// Round 8
// 543.523 us; speedup vs baseline: 2.7475x; 1.0105x over previous
//
#include <hip/hip_runtime.h>
#include <hip/hip_bf16.h>

typedef __hip_bfloat16 bf16;
using short8  = __attribute__((ext_vector_type(8))) short;
using float4v = __attribute__((ext_vector_type(4))) float;

static constexpr int N_ = 50000;   // nodes
static constexpr int E_ = 20000;   // hyperedges
static constexpr int M_ = 320000;  // incidence pairs
static constexpr int NPAD_ = 50048;  // 391*128 rows for MFMA grid
static constexpr int NB_E = (E_+255)/256;   // 79
static constexpr int NB_N = (N_+255)/256;   // 196

__device__ __forceinline__ float b2f(bf16 v){ return __bfloat162float(v); }
__device__ __forceinline__ float sigm(float x){ return 1.f/(1.f+__expf(-x)); }
__device__ __forceinline__ float u2f(unsigned short u){ return __uint_as_float(((unsigned)u)<<16); }
__device__ __forceinline__ unsigned short f2u(float f){ bf16 t=__float2bfloat16(f); return *(unsigned short*)&t; }

// ---------------- dtype sniff ----------------
__global__ __launch_bounds__(256) void k_sniff(const unsigned short* __restrict__ xb, int* flag){
  int tid = threadIdx.x;
  int sane = 0;
  for (int i = tid; i < 4096; i += 256){
    unsigned short u = xb[2*i];
    int ex = (u >> 7) & 0xFF;
    if ((u & 0x7FFF) == 0 || (ex >= 117 && ex <= 137)) sane++;
  }
  #pragma unroll
  for (int d=1; d<64; d<<=1) sane += __shfl_xor(sane, d, 64);
  __shared__ int wsh[4];
  if ((tid&63)==0) wsh[tid>>6] = sane;
  __syncthreads();
  if (tid==0){
    int tot = wsh[0]+wsh[1]+wsh[2]+wsh[3];
    *flag = (tot > 2048) ? 1 : 0;    // 1 = bf16 storage
  }
}

// ---------------- converts ----------------
__global__ __launch_bounds__(256) void k_cvt16(const void* __restrict__ src, bf16* __restrict__ dst,
                                               int n, const int* __restrict__ flag){
  int i = blockIdx.x*256 + threadIdx.x;
  if (i >= n) return;
  if (*flag) dst[i] = ((const bf16*)src)[i];
  else       dst[i] = __float2bfloat16(((const float*)src)[i]);
}

// all 10 small weight tensors -> fp32, one launch
__global__ __launch_bounds__(256) void k_cvtall(
    const void* s0, const void* s1, const void* s2, const void* s3, const void* s4,
    const void* s5, const void* s6, const void* s7, const void* s8, const void* s9,
    float* d0, float* d1, float* d2, float* d3, float* d4,
    float* d5, float* d6, float* d7, float* d8, float* d9,
    const int* __restrict__ flag){
  int i = blockIdx.x*256 + threadIdx.x;
  const void* src; float* dst; int off;
  if      (i < 1536)            { src=s0; dst=d0; off=i; }
  else if (i < 1536+81920)      { src=s1; dst=d1; off=i-1536; }
  else if (i < 83712+256)       { src=s2; dst=d2; off=i-83712; }
  else if (i < 83968+256)       { src=s3; dst=d3; off=i-83968; }
  else if (i < 84224+8)         { src=s4; dst=d4; off=i-84224; }
  else if (i < 84232+131072)    { src=s5; dst=d5; off=i-84232; }
  else if (i < 215304+131072)   { src=s6; dst=d6; off=i-215304; }
  else if (i < 346376+1536)     { src=s7; dst=d7; off=i-346376; }
  else if (i < 347912+512)      { src=s8; dst=d8; off=i-347912; }
  else if (i < 348424+512)      { src=s9; dst=d9; off=i-348424; }
  else return;
  if (*flag) dst[off] = b2f(((const bf16*)src)[off]);
  else       dst[off] = ((const float*)src)[off];
}

__global__ __launch_bounds__(256) void k_zero2(int* pe, int* pn){
  int i = blockIdx.x*256 + threadIdx.x;
  if (i < E_) pe[i] = 0;
  else if (i < E_+N_) pn[i-E_] = 0;
}

// ---------------- CSR build ----------------
__global__ __launch_bounds__(256) void k_hist(const int* __restrict__ eidx, const int* __restrict__ nidx,
                                              int* cnt_e, int* cnt_n){
  int m = blockIdx.x*256 + threadIdx.x;
  if (m < M_){ atomicAdd(&cnt_e[eidx[m]],1); atomicAdd(&cnt_n[nidx[m]],1); }
}

__device__ __forceinline__ void scan1_body(const int* cnt, int* off, int* bsum, int n, int blk){
  int tid = threadIdx.x, lane = tid&63, wid = tid>>6;
  int i = blk*256 + tid;
  int v = (i<n)? cnt[i] : 0;
  int s = v;
  #pragma unroll
  for (int d=1; d<64; d<<=1){ int t = __shfl_up(s, d, 64); if (lane>=d) s += t; }
  __shared__ int ws[4]; __shared__ int wo[4];
  if (lane==63) ws[wid] = s;
  __syncthreads();
  if (tid==0){ int a=0; for (int k=0;k<4;k++){ int t=ws[k]; wo[k]=a; a+=t; } bsum[blk]=a; }
  __syncthreads();
  if (i<n) off[i] = wo[wid] + s - v;
}

__global__ __launch_bounds__(256) void k_scan1m(const int* __restrict__ cnt_e, int* __restrict__ eoff, int* bsum_e,
                                                const int* __restrict__ cnt_n, int* __restrict__ noff, int* bsum_n){
  int b = blockIdx.x;
  if (b < NB_E) scan1_body(cnt_e, eoff, bsum_e, E_, b);
  else          scan1_body(cnt_n, noff, bsum_n, N_, b-NB_E);
}

__device__ __forceinline__ void scan2_body(int* bsum, int* off, int nb, int n){
  int tid = threadIdx.x, lane = tid&63, wid = tid>>6;
  int v = (tid<nb)? bsum[tid] : 0;
  int s = v;
  #pragma unroll
  for (int d=1; d<64; d<<=1){ int t = __shfl_up(s, d, 64); if (lane>=d) s += t; }
  __shared__ int ws[4]; __shared__ int wo[4];
  if (lane==63) ws[wid] = s;
  __syncthreads();
  if (tid==0){ int a=0; for (int k=0;k<4;k++){ int t=ws[k]; wo[k]=a; a+=t; } off[n]=a; }
  __syncthreads();
  if (tid<nb) bsum[tid] = wo[wid] + s - v;
}

__global__ __launch_bounds__(256) void k_scan2m(int* bsum_e, int* __restrict__ eoff,
                                                int* bsum_n, int* __restrict__ noff){
  if (blockIdx.x == 0) scan2_body(bsum_e, eoff, NB_E, E_);
  else                 scan2_body(bsum_n, noff, NB_N, N_);
}

__global__ __launch_bounds__(256) void k_scan3m(const int* __restrict__ bsum_e, int* __restrict__ eoff, int* cur_e,
                                                const int* __restrict__ bsum_n, int* __restrict__ noff, int* cur_n){
  int b = blockIdx.x;
  if (b < NB_E){
    int i = b*256 + threadIdx.x;
    if (i<E_){ int e = eoff[i] + bsum_e[b]; eoff[i]=e; cur_e[i]=e; }
  } else {
    int i = (b-NB_E)*256 + threadIdx.x;
    if (i<N_){ int e = noff[i] + bsum_n[b-NB_E]; noff[i]=e; cur_n[i]=e; }
  }
}

__global__ __launch_bounds__(256) void k_fill(const int* __restrict__ eidx, const int* __restrict__ nidx,
                                              int* cur_e, int* cur_n, int* ep, int* np){
  int m = blockIdx.x*256 + threadIdx.x;
  if (m < M_){
    int p = atomicAdd(&cur_e[eidx[m]],1); ep[p]=m;
    int q = atomicAdd(&cur_n[nidx[m]],1); np[q]=m;
  }
}

// ---------------- pre / wqe / bpack ----------------
__global__ __launch_bounds__(256) void k_pre(const float* __restrict__ tq, const float* __restrict__ w1,
                                             const float* __restrict__ b1, float* __restrict__ pre){
  int idx = blockIdx.x*256 + threadIdx.x;
  if (idx >= 768) return;
  int l = idx / 384, r = idx % 384;
  int t = r / 128, r2 = r % 128;
  int h = r2 >> 5, k = r2 & 31;
  const float* tp = tq + ((l*4+h)*3 + t)*64;
  const float* wp = w1 + (size_t)((l*4+h)*32 + k)*320 + 256;
  float s = b1[(l*4+h)*32 + k];
  for (int d=0; d<64; ++d) s += tp[d]*wp[d];
  pre[(l*3+t)*128 + r2] = s;
}

__global__ __launch_bounds__(256) void k_wqe(const float* __restrict__ wq_f, const float* __restrict__ ec_f,
                                             float* __restrict__ wqe){
  int b = blockIdx.x;
  int l = b/12, ht = b%12, h = ht/3, t = ht%3;
  int d = threadIdx.x;
  const float* ecp = ec_f + ((l*4+h)*3 + t)*64;
  const float* wqp = wq_f + (size_t)((l*4+h)*64)*256;
  float s = 0.f;
  for (int o=0;o<64;++o) s += ecp[o]*wqp[o*256 + d];
  wqe[(size_t)(l*12+ht)*256 + d] = s;
}

// pack B panel with V cols PERMUTED to the V16 interleave order
__global__ __launch_bounds__(256) void k_bpack(const float* __restrict__ wv_f, const float* __restrict__ w1_f,
                                               const float* __restrict__ wqe, bf16* __restrict__ Bp){
  int idx = blockIdx.x*256 + threadIdx.x;
  if (idx >= 2*448*256) return;
  int l = idx / (448*256), r = idx % (448*256);
  int c = r >> 8, k = r & 255;
  float v = 0.f;
  if (c < 256){
    int dd = c >> 2, h = c & 3;
    v = wv_f[(size_t)l*65536 + (size_t)(h*64+dd)*256 + k];
  }
  else if (c < 384) v = w1_f[(size_t)l*40960 + (size_t)(c-256)*320 + k];
  else if (c < 396) v = wqe[(size_t)(l*12 + c-384)*256 + k];
  Bp[idx] = __float2bfloat16(v);
}

// ---------------- MFMA GEMM, XCD-swizzled, SOFTWARE-PIPELINED K-loop ----------------
// 2 register stage-buffers of BK=64 (12 short8 each); load stage s+1 while MFMA-ing stage s.
// launch_bounds(256,3): ~170 VGPR budget so both buffers stay in registers -> 12 loads in flight.
__global__ __launch_bounds__(256,3) void k_mgemm(const bf16* __restrict__ A16, const bf16* __restrict__ Bp,
    bf16* __restrict__ V16, bf16* __restrict__ Hb16, float* __restrict__ S){
  int g = blockIdx.x;
  int r8 = g & 7, kk = g >> 3;
  int x = kk / 49, yhi = kk % 49;
  int y = yhi*8 + r8;
  if (y >= 391 || x >= 7) return;
  int wid = threadIdx.x >> 6, lane = threadIdx.x & 63;
  int q = lane >> 4, li = lane & 15;
  int row0 = y*128 + wid*32;
  int col0 = x*64;
  float4v acc[2][4];
  #pragma unroll
  for (int i=0;i<2;i++)
    #pragma unroll
    for (int j=0;j<4;j++) acc[i][j] = (float4v)(0.f);
  const bf16* a0p = A16 + (size_t)(row0 + li)*256;
  const bf16* a1p = A16 + (size_t)(row0 + 16 + li)*256;
  const bf16* bp  = Bp  + (size_t)(col0 + li)*256;

  short8 bA0[2][2], bA1[2][2], bB[2][4][2];   // [buf][k-half], B:[buf][j][k-half]
  auto load_stage = [&](int st, int b){
    int ko = st*64 + q*8;
    bA0[b][0] = *(const short8*)(a0p + ko);       bA0[b][1] = *(const short8*)(a0p + ko + 32);
    bA1[b][0] = *(const short8*)(a1p + ko);       bA1[b][1] = *(const short8*)(a1p + ko + 32);
    #pragma unroll
    for (int j=0;j<4;j++){
      bB[b][j][0] = *(const short8*)(bp + j*16*256 + ko);
      bB[b][j][1] = *(const short8*)(bp + j*16*256 + ko + 32);
    }
  };
  load_stage(0, 0);
  #pragma unroll
  for (int st=0; st<4; ++st){
    int b = st & 1;
    if (st < 3) load_stage(st+1, b^1);
    #pragma unroll
    for (int kh=0; kh<2; ++kh){
      #pragma unroll
      for (int j=0;j<4;j++){
        acc[0][j] = __builtin_amdgcn_mfma_f32_16x16x32_bf16(bA0[b][kh], bB[b][j][kh], acc[0][j],0,0,0);
        acc[1][j] = __builtin_amdgcn_mfma_f32_16x16x32_bf16(bA1[b][kh], bB[b][j][kh], acc[1][j],0,0,0);
      }
    }
  }
  #pragma unroll
  for (int i=0;i<2;i++){
    #pragma unroll
    for (int r=0;r<4;r++){
      int grow = row0 + i*16 + q*4 + r;
      if (grow >= N_) continue;
      #pragma unroll
      for (int j=0;j<4;j++){
        int gc = col0 + j*16 + li;
        float v = acc[i][j][r];
        if (gc < 256)      V16 [(size_t)grow*256 + gc]       = __float2bfloat16(v);  // contiguous (permuted)
        else if (gc < 384) Hb16[(size_t)grow*128 + gc - 256] = __float2bfloat16(v);
        else if (gc < 396) S   [(size_t)grow*12  + gc - 384] = v;
      }
    }
  }
}

// ---------------- per-node gate (Hb bf16) ----------------
__global__ __launch_bounds__(256) void k_gate(const unsigned short* __restrict__ Hb16, const float* __restrict__ S,
    const float* __restrict__ pre_l, const float* __restrict__ w2_l, const float* __restrict__ b2_l,
    const int* __restrict__ ntype, float* __restrict__ G){
  int node = blockIdx.x*4 + (threadIdx.x>>6);
  int lane = threadIdx.x & 63;
  if (node >= N_) return;
  int typ = ntype[node];
  const float* pr = pre_l + typ*128;
  float v0 = tanhf(u2f(Hb16[(size_t)node*128 + lane])      + pr[lane]);
  float v1 = tanhf(u2f(Hb16[(size_t)node*128 + 64 + lane]) + pr[64+lane]);
  float p0 = v0 * w2_l[lane];
  float p1 = v1 * w2_l[64+lane];
  #pragma unroll
  for (int d=1; d<32; d<<=1){ p0 += __shfl_xor(p0,d,64); p1 += __shfl_xor(p1,d,64); }
  float at0 = sigm(__shfl(p0, 0,64) + b2_l[0]);
  float at1 = sigm(__shfl(p0,32,64) + b2_l[1]);
  float at2 = sigm(__shfl(p1, 0,64) + b2_l[2]);
  float at3 = sigm(__shfl(p1,32,64) + b2_l[3]);
  if (lane < 12){
    int h = lane / 3, t = lane % 3;
    float sv = S[(size_t)node*12 + lane];
    float lr = (sv > 0.f) ? sv : 0.2f*sv;
    float av = (h==0)? at0 : (h==1)? at1 : (h==2)? at2 : at3;
    G[(size_t)node*12 + t*4 + h] = lr * av;
  }
}

// ---------------- per-edge softmax + edge_feat (single-pass, pipelined gather) ----------------
__global__ __launch_bounds__(256) void k_edge(const int* __restrict__ eoff, const int* __restrict__ ep,
    const int* __restrict__ nidx, const int* __restrict__ etype,
    const float* __restrict__ G, const unsigned short* __restrict__ V16,
    float* __restrict__ attn, unsigned short* __restrict__ EF16){
  int e = blockIdx.x*4 + (threadIdx.x>>6);
  int lane = threadIdx.x & 63;
  if (e >= E_) return;
  int beg = eoff[e], end = eoff[e+1];
  int deg = end - beg;
  if (deg == 0) return;
  int t = etype[e];
  float a0=0,a1=0,a2=0,a3=0;

  if (deg <= 64){
    int i = beg + lane;
    int m = -1, n = 0;
    float4 g; g.x=g.y=g.z=g.w=-1e30f;
    if (lane < deg){
      m = ep[i]; n = nidx[m];
      g = *(const float4*)(G + (size_t)n*12 + t*4);
    }
    float mx0=g.x, mx1=g.y, mx2=g.z, mx3=g.w;
    #pragma unroll
    for (int d=1; d<64; d<<=1){
      mx0=fmaxf(mx0,__shfl_xor(mx0,d,64)); mx1=fmaxf(mx1,__shfl_xor(mx1,d,64));
      mx2=fmaxf(mx2,__shfl_xor(mx2,d,64)); mx3=fmaxf(mx3,__shfl_xor(mx3,d,64));
    }
    float ex0=0,ex1=0,ex2=0,ex3=0;
    if (lane < deg){
      ex0=__expf(g.x-mx0); ex1=__expf(g.y-mx1); ex2=__expf(g.z-mx2); ex3=__expf(g.w-mx3);
    }
    float s0=ex0,s1=ex1,s2=ex2,s3=ex3;
    #pragma unroll
    for (int d=1; d<64; d<<=1){
      s0+=__shfl_xor(s0,d,64); s1+=__shfl_xor(s1,d,64);
      s2+=__shfl_xor(s2,d,64); s3+=__shfl_xor(s3,d,64);
    }
    float4 w; w.x=ex0/s0; w.y=ex1/s1; w.z=ex2/s2; w.w=ex3/s3;
    if (lane < deg) *(float4*)(attn + (size_t)m*4) = w;
    auto ldrow = [&](int j)->ushort4{
      int nn = __shfl(n, j, 64);
      return *(const ushort4*)(V16 + (size_t)nn*256 + (lane<<2));
    };
    ushort4 v0v,v1v,v2v,v3v;
    if (deg>0) v0v=ldrow(0);
    if (deg>1) v1v=ldrow(1);
    if (deg>2) v2v=ldrow(2);
    if (deg>3) v3v=ldrow(3);
    for (int j=0;j<deg;j+=4){
      { float wx=__shfl(w.x,j,64),wy=__shfl(w.y,j,64),wz=__shfl(w.z,j,64),wq=__shfl(w.w,j,64);
        a0+=wx*u2f(v0v.x); a1+=wy*u2f(v0v.y); a2+=wz*u2f(v0v.z); a3+=wq*u2f(v0v.w);
        if (j+4<deg) v0v=ldrow(j+4); }
      if (j+1<deg){
        float wx=__shfl(w.x,j+1,64),wy=__shfl(w.y,j+1,64),wz=__shfl(w.z,j+1,64),wq=__shfl(w.w,j+1,64);
        a0+=wx*u2f(v1v.x); a1+=wy*u2f(v1v.y); a2+=wz*u2f(v1v.z); a3+=wq*u2f(v1v.w);
        if (j+5<deg) v1v=ldrow(j+5); }
      if (j+2<deg){
        float wx=__shfl(w.x,j+2,64),wy=__shfl(w.y,j+2,64),wz=__shfl(w.z,j+2,64),wq=__shfl(w.w,j+2,64);
        a0+=wx*u2f(v2v.x); a1+=wy*u2f(v2v.y); a2+=wz*u2f(v2v.z); a3+=wq*u2f(v2v.w);
        if (j+6<deg) v2v=ldrow(j+6); }
      if (j+3<deg){
        float wx=__shfl(w.x,j+3,64),wy=__shfl(w.y,j+3,64),wz=__shfl(w.z,j+3,64),wq=__shfl(w.w,j+3,64);
        a0+=wx*u2f(v3v.x); a1+=wy*u2f(v3v.y); a2+=wz*u2f(v3v.z); a3+=wq*u2f(v3v.w);
        if (j+7<deg) v3v=ldrow(j+7); }
    }
  } else {
    float mx0=-1e30f, mx1=-1e30f, mx2=-1e30f, mx3=-1e30f;
    for (int i=beg+lane; i<end; i+=64){
      int m = ep[i]; int n = nidx[m];
      float4 g = *(const float4*)(G + (size_t)n*12 + t*4);
      mx0=fmaxf(mx0,g.x); mx1=fmaxf(mx1,g.y); mx2=fmaxf(mx2,g.z); mx3=fmaxf(mx3,g.w);
    }
    #pragma unroll
    for (int d=1; d<64; d<<=1){
      mx0=fmaxf(mx0,__shfl_xor(mx0,d,64)); mx1=fmaxf(mx1,__shfl_xor(mx1,d,64));
      mx2=fmaxf(mx2,__shfl_xor(mx2,d,64)); mx3=fmaxf(mx3,__shfl_xor(mx3,d,64));
    }
    float sm0=0,sm1=0,sm2=0,sm3=0;
    for (int i=beg+lane; i<end; i+=64){
      int m = ep[i]; int n = nidx[m];
      float4 g = *(const float4*)(G + (size_t)n*12 + t*4);
      sm0+=__expf(g.x-mx0); sm1+=__expf(g.y-mx1); sm2+=__expf(g.z-mx2); sm3+=__expf(g.w-mx3);
    }
    #pragma unroll
    for (int d=1; d<64; d<<=1){
      sm0+=__shfl_xor(sm0,d,64); sm1+=__shfl_xor(sm1,d,64);
      sm2+=__shfl_xor(sm2,d,64); sm3+=__shfl_xor(sm3,d,64);
    }
    float inv0=1.f/sm0, inv1=1.f/sm1, inv2=1.f/sm2, inv3=1.f/sm3;
    for (int i=beg+lane; i<end; i+=64){
      int m = ep[i]; int n = nidx[m];
      float4 g = *(const float4*)(G + (size_t)n*12 + t*4);
      float4 w;
      w.x=__expf(g.x-mx0)*inv0; w.y=__expf(g.y-mx1)*inv1;
      w.z=__expf(g.z-mx2)*inv2; w.w=__expf(g.w-mx3)*inv3;
      *(float4*)(attn + (size_t)m*4) = w;
    }
    for (int i=beg; i<end; ++i){
      int m = ep[i]; int n = nidx[m];
      float4 g = *(const float4*)(G + (size_t)n*12 + t*4);
      float w0=__expf(g.x-mx0)*inv0, w1=__expf(g.y-mx1)*inv1;
      float w2=__expf(g.z-mx2)*inv2, w3=__expf(g.w-mx3)*inv3;
      ushort4 v = *(const ushort4*)(V16 + (size_t)n*256 + lane*4);
      a0 += w0*u2f(v.x); a1 += w1*u2f(v.y); a2 += w2*u2f(v.z); a3 += w3*u2f(v.w);
    }
  }
  ushort4 ev; ev.x=f2u(a0); ev.y=f2u(a1); ev.z=f2u(a2); ev.w=f2u(a3);
  *(ushort4*)(EF16 + (size_t)e*256 + lane*4) = ev;
}

// ---------------- per-node gather + residual + LayerNorm (pipelined) ----------------
__global__ __launch_bounds__(256) void k_node(const int* __restrict__ noff, const int* __restrict__ np,
    const int* __restrict__ eidx, const float* __restrict__ attn, const unsigned short* __restrict__ EF16,
    const float* __restrict__ lng, const float* __restrict__ lnb,
    bf16* __restrict__ h16, void* __restrict__ outv, const int* __restrict__ flag, int last){
  int n = blockIdx.x*4 + (threadIdx.x>>6);
  int lane = threadIdx.x & 63;
  if (n >= N_) return;
  float f0=0,f1=0,f2=0,f3=0;
  int beg = noff[n], end = noff[n+1];
  int deg = end - beg;
  if (deg > 0 && deg <= 64){
    int i = beg + lane;
    int e = 0;
    float4 w; w.x=w.y=w.z=w.w=0.f;
    if (lane < deg){
      int m = np[i]; e = eidx[m];
      w = *(const float4*)(attn + (size_t)m*4);
    }
    auto ldrow = [&](int j)->ushort4{
      int ee = __shfl(e, j, 64);
      return *(const ushort4*)(EF16 + (size_t)ee*256 + (lane<<2));
    };
    ushort4 v0v,v1v,v2v,v3v;
    if (deg>0) v0v=ldrow(0);
    if (deg>1) v1v=ldrow(1);
    if (deg>2) v2v=ldrow(2);
    if (deg>3) v3v=ldrow(3);
    for (int j=0;j<deg;j+=4){
      { float wx=__shfl(w.x,j,64),wy=__shfl(w.y,j,64),wz=__shfl(w.z,j,64),wq=__shfl(w.w,j,64);
        f0+=wx*u2f(v0v.x); f1+=wy*u2f(v0v.y); f2+=wz*u2f(v0v.z); f3+=wq*u2f(v0v.w);
        if (j+4<deg) v0v=ldrow(j+4); }
      if (j+1<deg){
        float wx=__shfl(w.x,j+1,64),wy=__shfl(w.y,j+1,64),wz=__shfl(w.z,j+1,64),wq=__shfl(w.w,j+1,64);
        f0+=wx*u2f(v1v.x); f1+=wy*u2f(v1v.y); f2+=wz*u2f(v1v.z); f3+=wq*u2f(v1v.w);
        if (j+5<deg) v1v=ldrow(j+5); }
      if (j+2<deg){
        float wx=__shfl(w.x,j+2,64),wy=__shfl(w.y,j+2,64),wz=__shfl(w.z,j+2,64),wq=__shfl(w.w,j+2,64);
        f0+=wx*u2f(v2v.x); f1+=wy*u2f(v2v.y); f2+=wz*u2f(v2v.z); f3+=wq*u2f(v2v.w);
        if (j+6<deg) v2v=ldrow(j+6); }
      if (j+3<deg){
        float wx=__shfl(w.x,j+3,64),wy=__shfl(w.y,j+3,64),wz=__shfl(w.z,j+3,64),wq=__shfl(w.w,j+3,64);
        f0+=wx*u2f(v3v.x); f1+=wy*u2f(v3v.y); f2+=wz*u2f(v3v.z); f3+=wq*u2f(v3v.w);
        if (j+7<deg) v3v=ldrow(j+7); }
    }
  } else if (deg > 64){
    for (int i=beg; i<end; ++i){
      int m = np[i]; int e = eidx[m];
      float4 w = *(const float4*)(attn + (size_t)m*4);
      ushort4 v = *(const ushort4*)(EF16 + (size_t)e*256 + lane*4);
      f0 += w.x*u2f(v.x); f1 += w.y*u2f(v.y); f2 += w.z*u2f(v.z); f3 += w.w*u2f(v.w);
    }
  }
  const bf16* hp = h16 + (size_t)n*256;
  float h0 = b2f(hp[lane])+f0, h1 = b2f(hp[64+lane])+f1, h2 = b2f(hp[128+lane])+f2, h3 = b2f(hp[192+lane])+f3;
  float s = h0+h1+h2+h3;
  #pragma unroll
  for (int d=1; d<64; d<<=1) s += __shfl_xor(s,d,64);
  float mean = s * (1.f/256.f);
  float d0=h0-mean, d1=h1-mean, d2=h2-mean, d3=h3-mean;
  float vv = d0*d0+d1*d1+d2*d2+d3*d3;
  #pragma unroll
  for (int d=1; d<64; d<<=1) vv += __shfl_xor(vv,d,64);
  float rstd = rsqrtf(vv*(1.f/256.f) + 1e-5f);
  float o0 = d0*rstd*lng[lane]     + lnb[lane];
  float o1 = d1*rstd*lng[64+lane]  + lnb[64+lane];
  float o2 = d2*rstd*lng[128+lane] + lnb[128+lane];
  float o3 = d3*rstd*lng[192+lane] + lnb[192+lane];
  if (last){
    if (*flag){
      bf16* op = (bf16*)outv + (size_t)n*256;
      op[lane]=__float2bfloat16(o0); op[64+lane]=__float2bfloat16(o1);
      op[128+lane]=__float2bfloat16(o2); op[192+lane]=__float2bfloat16(o3);
    } else {
      float* op = (float*)outv + (size_t)n*256;
      op[lane]=o0; op[64+lane]=o1; op[128+lane]=o2; op[192+lane]=o3;
    }
  } else {
    bf16* o16 = h16 + (size_t)n*256;
    o16[lane]=__float2bfloat16(o0); o16[64+lane]=__float2bfloat16(o1);
    o16[128+lane]=__float2bfloat16(o2); o16[192+lane]=__float2bfloat16(o3);
  }
}

extern "C" void kernel_launch(void* const* d_in, const int* in_sizes, int n_in,
                              void* d_out, int out_size, void* d_ws, size_t ws_size,
                              hipStream_t stream){
  const void* x    = d_in[0];
  const int* ntype = (const int*)d_in[1];
  const int* etype = (const int*)d_in[2];
  const int* nidx  = (const int*)d_in[3];
  const int* eidx  = (const int*)d_in[4];
  (void)in_sizes; (void)n_in; (void)out_size; (void)ws_size;

  char* ws = (char*)d_ws;
  size_t o = 0;
  auto alloc = [&](size_t b)->char*{ char* r = ws + o; o = (o + b + 255) & ~(size_t)255; return r; };
  int*   flag = (int*)  alloc(256);
  char*  R2   =         alloc((size_t)20000000);          // Hb16+S (gemm->gate) / attn+EF16 (edge->node)
  float* G    = (float*)alloc((size_t)N_*12*4);
  float* tq_f  = (float*)alloc(1536*4);
  float* w1_f  = (float*)alloc(81920*4);
  float* b1_f  = (float*)alloc(256*4);
  float* w2_f  = (float*)alloc(256*4);
  float* b2_f  = (float*)alloc(8*4);
  float* wq_f  = (float*)alloc(131072*4);
  float* wv_f  = (float*)alloc(131072*4);
  float* ec_f  = (float*)alloc(1536*4);
  float* lng_f = (float*)alloc(512*4);
  float* lnb_f = (float*)alloc(512*4);
  float* wqe   = (float*)alloc(6144*4);
  float* pre   = (float*)alloc(768*4);
  int* cnt_e  = (int*)alloc((size_t)E_*4);
  int* cnt_n  = (int*)alloc((size_t)N_*4);
  int* eoff   = (int*)alloc((size_t)(E_+1)*4);
  int* noff   = (int*)alloc((size_t)(N_+1)*4);
  int* cur_e  = (int*)alloc((size_t)E_*4);
  int* cur_n  = (int*)alloc((size_t)N_*4);
  int* ep     = (int*)alloc((size_t)M_*4);
  int* np     = (int*)alloc((size_t)M_*4);
  int* bsum_e = (int*)alloc(256*4);
  int* bsum_n = (int*)alloc(256*4);
  bf16* h16   = (bf16*)alloc((size_t)NPAD_*256*2);        // 25.6 MB bf16 hidden state (A for MFMA)
  bf16* Bp    = (bf16*)alloc((size_t)2*448*256*2);
  bf16* V16   = (bf16*)alloc((size_t)N_*256*2);           // 25.6 MB interleaved [n][d][h]

  bf16*  Hb16 = (bf16*)R2;                                 // 12.8 MB
  float* S    = (float*)(R2 + 16777216);                   // 2.4 MB
  float* attn = (float*)R2;                                // 5.12 MB
  unsigned short* EF16 = (unsigned short*)(R2 + 5242880);  // 10.24 MB (ends 15.48M < S)

  k_sniff<<<1, 256, 0, stream>>>((const unsigned short*)x, flag);
  k_cvt16<<<(N_*256+255)/256, 256, 0, stream>>>(x, h16, N_*256, flag);
  k_cvtall<<<(348936+255)/256, 256, 0, stream>>>(
      d_in[5], d_in[6], d_in[7], d_in[8], d_in[9],
      d_in[10], d_in[11], d_in[12], d_in[13], d_in[14],
      tq_f, w1_f, b1_f, w2_f, b2_f, wq_f, wv_f, ec_f, lng_f, lnb_f, flag);

  k_zero2<<<(E_+N_+255)/256, 256, 0, stream>>>(cnt_e, cnt_n);
  k_hist<<<M_/256, 256, 0, stream>>>(eidx, nidx, cnt_e, cnt_n);
  k_scan1m<<<NB_E+NB_N, 256, 0, stream>>>(cnt_e, eoff, bsum_e, cnt_n, noff, bsum_n);
  k_scan2m<<<2, 256, 0, stream>>>(bsum_e, eoff, bsum_n, noff);
  k_scan3m<<<NB_E+NB_N, 256, 0, stream>>>(bsum_e, eoff, cur_e, bsum_n, noff, cur_n);
  k_fill<<<M_/256, 256, 0, stream>>>(eidx, nidx, cur_e, cur_n, ep, np);
  k_pre<<<3, 256, 0, stream>>>(tq_f, w1_f, b1_f, pre);
  k_wqe<<<24, 256, 0, stream>>>(wq_f, ec_f, wqe);
  k_bpack<<<(2*448*256+255)/256, 256, 0, stream>>>(wv_f, w1_f, wqe, Bp);

  for (int l=0; l<2; ++l){
    k_mgemm<<<2744, 256, 0, stream>>>(h16, Bp + (size_t)l*448*256, V16, Hb16, S);
    k_gate<<<12500, 256, 0, stream>>>((const unsigned short*)Hb16, S, pre + l*384,
                                      w2_f + l*128, b2_f + l*4, ntype, G);
    k_edge<<<5000, 256, 0, stream>>>(eoff, ep, nidx, etype, G, (const unsigned short*)V16, attn, EF16);
    k_node<<<12500, 256, 0, stream>>>(noff, np, eidx, attn, EF16, lng_f + l*256, lnb_f + l*256,
                                      h16, d_out, flag, l==1);
  }
}